// Round 5
// baseline (379.024 us; speedup 1.0000x reference)
//
#include <hip/hip_runtime.h>

typedef unsigned short u16;
typedef unsigned int   u32;
typedef __bf16 bf16x8 __attribute__((ext_vector_type(8)));
typedef float  f32x4  __attribute__((ext_vector_type(4)));

#define DD 1024

__device__ __forceinline__ u16 f2bf(float f) {
  u32 u = __float_as_uint(f);
  u32 r = (u + 0x7FFFu + ((u >> 16) & 1u)) >> 16;
  return (u16)r;
}

// async global->LDS, 16B per lane. Dest must be wave-uniform-base + lane*16.
typedef const __attribute__((address_space(1))) void* gp1;
typedef __attribute__((address_space(3))) void* lp3;
__device__ __forceinline__ void gll16(const void* g, void* l) {
  __builtin_amdgcn_global_load_lds((gp1)g, (lp3)l, 16, 0, 0);
}

// ---------------------------------------------------------------------------
// k01: merged pre-kernel. HEAVY BLOCKS FIRST (dispatch order = start order;
// round-4 regression was the heavy tail starting after 1024 streamers).
// blocks 0..31    : AWBW[16][1024] = {A,B}@W_base (fp32 atomics, split-i)
// blocks 32..35   : Mbuf: 4 Gram 8x8 (A.Us, B.Us, A.Ul, B.Ul)
// blocks 36..39   : Pb[32][1024] = bf16([Ao;Bo;Us;Ul])
// blocks 40..295  : Wt[n][k] = bf16(W[k][n])  (transpose + convert)
// blocks 296..1319: x fp32 -> bf16 (XB) + pooled sums, 16 rows/block,
//                   XCD row-swizzle matching k3a's reader XCD.
// ---------------------------------------------------------------------------
template <bool XB>
__global__ __launch_bounds__(256) void k01_pre(
    const float* __restrict__ x, u16* __restrict__ xb, float* __restrict__ pooled,
    const float* __restrict__ W,
    const float* __restrict__ Ao, const float* __restrict__ Bo,
    const float* __restrict__ Us, const float* __restrict__ Ul,
    float* __restrict__ AWBW, float* __restrict__ Mbuf,
    u16* __restrict__ Pb, u16* __restrict__ Wt) {
  const int tid = threadIdx.x;
  const int bid = blockIdx.x;
  if (bid >= 296) {
    const int i = bid - 296;                   // dispatch XCD = i%8 (296%8==0)
    const int xcd = i & 7, local = i >> 3;
    const int rb = xcd * 128 + local;          // row-block 0..1023
    const int b = rb >> 8;
    const long r0 = (long)rb * 16;
    const int c0 = tid * 4;
    float s0 = 0.f, s1 = 0.f, s2 = 0.f, s3 = 0.f;
    for (int r = 0; r < 16; r++) {
      float4 v = *(const float4*)(x + (r0 + r) * DD + c0);
      if (XB) {
        ushort4 o;
        o.x = f2bf(v.x); o.y = f2bf(v.y); o.z = f2bf(v.z); o.w = f2bf(v.w);
        *(ushort4*)(xb + (r0 + r) * DD + c0) = o;
      }
      s0 += v.x; s1 += v.y; s2 += v.z; s3 += v.w;
    }
    atomicAdd(&pooled[b * DD + c0 + 0], s0);
    atomicAdd(&pooled[b * DD + c0 + 1], s1);
    atomicAdd(&pooled[b * DD + c0 + 2], s2);
    atomicAdd(&pooled[b * DD + c0 + 3], s3);
    return;
  }
  if (bid < 32) {
    __shared__ float red2[2][128][16];
    const int m = bid;
    const int n = (m & 7) * 128 + (tid & 127), q = m >> 3, ih = tid >> 7;
    float acc[16];
#pragma unroll
    for (int k = 0; k < 16; k++) acc[k] = 0.f;
    const int ib = q * 256 + ih * 128;
    for (int i = ib; i < ib + 128; i++) {
      float wv = W[(long)i * DD + n];
#pragma unroll
      for (int k = 0; k < 8; k++) {
        acc[k]     += Ao[k * DD + i] * wv;
        acc[k + 8] += Bo[k * DD + i] * wv;
      }
    }
#pragma unroll
    for (int k = 0; k < 16; k++) red2[ih][tid & 127][k] = acc[k];
    __syncthreads();
    if (ih == 0)
#pragma unroll
      for (int k = 0; k < 16; k++)
        atomicAdd(&AWBW[k * DD + n], red2[0][tid][k] + red2[1][tid][k]);
  } else if (bid < 36) {
    __shared__ float red[64][4];
    const int m = bid - 32;
    const float* L  = (m == 0 || m == 2) ? Ao : Bo;
    const float* Rr = (m < 2) ? Us : Ul;
    const int o = tid >> 2, ch = tid & 3;
    const int k = o >> 3, kp = o & 7;
    float a = 0.f;
    for (int i = ch * 256; i < ch * 256 + 256; i++)
      a += L[(long)k * DD + i] * Rr[(long)kp * DD + i];
    red[o][ch] = a;
    __syncthreads();
    if (tid < 64) Mbuf[m * 64 + tid] = red[tid][0] + red[tid][1] + red[tid][2] + red[tid][3];
  } else if (bid < 40) {
    const int m = bid - 36;
    const float* src = m == 0 ? Ao : m == 1 ? Bo : m == 2 ? Us : Ul;
#pragma unroll
    for (int j = 0; j < 8; j++)
      for (int q = 0; q < 4; q++) {
        int i = q * 256 + tid;
        Pb[(m * 8 + j) * DD + i] = f2bf(src[j * DD + i]);
      }
  } else {
    __shared__ u16 T[64][66];
    const int t = bid - 40, tr = t >> 4, tc = t & 15;
#pragma unroll
    for (int q2 = 0; q2 < 16; q2++) {
      int idx = q2 * 256 + tid, r = idx >> 6, c = idx & 63;
      T[r][c] = f2bf(W[(long)(tr * 64 + r) * DD + tc * 64 + c]);
    }
    __syncthreads();
#pragma unroll
    for (int q2 = 0; q2 < 16; q2++) {
      int idx = q2 * 256 + tid, c = idx >> 6, r = idx & 63;
      Wt[(long)(tc * 64 + c) * DD + tr * 64 + r] = T[r][c];
    }
  }
}

// ---------------------------------------------------------------------------
// k3a_mega (mode A): conditioner chain folded in as blocks 0..39 (dispatched
// first -> co-resident; GEMM blocks only need gates/RwT AFTER their ~85us
// main loop, so the conditioner runs entirely in its shadow).
// blocks 0..31 : LN + z@Wc1 partial -> h1pre atomics; signal cntH.
// blocks 32..35: spin cntH==32 -> gates[b]; release fence; signal cntG.
// blocks 36..39: pack RwT (AWBW from k01, kernel boundary); fence; cntG.
// blocks 40..1063: 128x128 GEMM (double-buffered gll16, XCD swizzle);
//                  spin cntG==8 + acquire fence before the post-loop phase.
// Conditioner branches read Wc1/Wc2 straight from L2 (no big LDS stage) so
// kernel LDS stays 38912 -> 3 blocks/CU preserved.
// ---------------------------------------------------------------------------
__global__ __launch_bounds__(256, 3) void k3a_mega(
    const u16* __restrict__ xb, const u16* __restrict__ Wt,
    const u16* __restrict__ Pb, const float* __restrict__ Mbuf,
    const float* __restrict__ bb,
    const float* __restrict__ pooledsum,
    const float* __restrict__ lng, const float* __restrict__ lnb,
    const float* __restrict__ Wc1, float* __restrict__ h1pre,
    const float* __restrict__ AWBW, const float* Vs, const float* Vl,
    const float* bc1, const float* Wc2, const float* bc2,
    const float* Wrg, const float* brg, const float* Wrc, const float* brc,
    const float* Wsg, const float* bsg, const float* Wlc, const float* blc,
    float* __restrict__ gates, u16* __restrict__ RwT,
    u32* __restrict__ cntH, u32* __restrict__ cntG,
    float* __restrict__ out) {
  __shared__ __align__(16) char smem[38912];
  const int tid = threadIdx.x;
  const int bid = blockIdx.x;

  if (bid < 32) {
    // ---- LN + z@Wc1 chunk partial ----
    float* zs  = (float*)smem;            // 1024 f32
    float* red = (float*)(smem + 4096);   // 256 f32
    const int b = bid >> 3, ch = bid & 7;
    float4 v = *(const float4*)(pooledsum + b * DD + tid * 4);
    v.x *= (1.f / 4096.f); v.y *= (1.f / 4096.f); v.z *= (1.f / 4096.f); v.w *= (1.f / 4096.f);
    float s = v.x + v.y + v.z + v.w;
    float sq = v.x * v.x + v.y * v.y + v.z * v.z + v.w * v.w;
    red[tid] = s; __syncthreads();
    for (int st = 128; st > 0; st >>= 1) { if (tid < st) red[tid] += red[tid + st]; __syncthreads(); }
    float mu = red[0] * (1.f / 1024.f);
    __syncthreads();
    red[tid] = sq; __syncthreads();
    for (int st = 128; st > 0; st >>= 1) { if (tid < st) red[tid] += red[tid + st]; __syncthreads(); }
    float var = red[0] * (1.f / 1024.f) - mu * mu;
    float rs = rsqrtf(var + 1e-5f);
    __syncthreads();
    {
      float4 g = *(const float4*)(lng + tid * 4);
      float4 be = *(const float4*)(lnb + tid * 4);
      zs[tid * 4 + 0] = (v.x - mu) * rs * g.x + be.x;
      zs[tid * 4 + 1] = (v.y - mu) * rs * g.y + be.y;
      zs[tid * 4 + 2] = (v.z - mu) * rs * g.z + be.z;
      zs[tid * 4 + 3] = (v.w - mu) * rs * g.w + be.w;
    }
    __syncthreads();
    const int j = tid & 127, half = tid >> 7;
    float a = 0.f;
#pragma unroll 8
    for (int dd = 0; dd < 64; dd++) {
      int ldi = half * 64 + dd;
      a += zs[ch * 128 + ldi] * Wc1[(long)ch * 16384 + ldi * 128 + j];
    }
    red[tid] = a;
    __syncthreads();
    if (tid < 128) atomicAdd(&h1pre[b * 128 + tid], red[tid] + red[tid + 128]);
    __syncthreads();
    if (tid == 0) atomicAdd(cntH, 1u);
  } else if (bid < 36) {
    // ---- gates for batch b ----
    float* h1s = (float*)smem;            // 128 f32
    float* hb  = (float*)(smem + 512);    // 128 f32
    float* red = (float*)(smem + 1024);   // 256 f32
    const int b = bid - 32;
    if (tid == 0) {
      while (atomicAdd(cntH, 0u) < 32u) __builtin_amdgcn_s_sleep(8);
    }
    __syncthreads();
    if (tid < 128) {
      float hv = atomicAdd(&h1pre[b * 128 + tid], 0.f) + bc1[tid];
      float th = tanhf(0.7978845608028654f * (hv + 0.044715f * hv * hv * hv));
      h1s[tid] = 0.5f * hv * (1.f + th);
    }
    __syncthreads();
    const int i = tid & 127, half = tid >> 7;
    float a = 0.f;
#pragma unroll 8
    for (int k = 0; k < 64; k++) {
      int kk = half * 64 + k;
      a += h1s[kk] * Wc2[kk * 128 + i];
    }
    red[tid] = a;
    __syncthreads();
    if (tid < 128) hb[tid] = red[tid] + red[tid + 128] + bc2[tid];
    __syncthreads();
    if (tid < 25) {
      float acc;
      if (tid == 0) {
        acc = brg[0];
        for (int k = 0; k < 128; k++) acc += hb[k] * Wrg[k];
        red[0] = 1.f / (1.f + expf(-acc));
      } else if (tid < 9) {
        int ci = tid - 1; acc = brc[ci];
        for (int k = 0; k < 128; k++) acc += hb[k] * Wrc[k * 8 + ci];
        red[tid] = tanhf(acc);
      } else if (tid < 17) {
        int ci = tid - 9; acc = bsg[ci];
        for (int k = 0; k < 128; k++) acc += hb[k] * Wsg[k * 8 + ci];
        red[tid] = tanhf(acc);
      } else {
        int ci = tid - 17; acc = blc[ci];
        for (int k = 0; k < 128; k++) acc += hb[k] * Wlc[k * 8 + ci];
        red[tid] = tanhf(acc);
      }
    }
    __syncthreads();
    if (tid < 24) {
      float g = red[0];
      gates[b * 32 + tid] = (tid < 8) ? g * red[1 + tid] : red[1 + tid];
    }
    __syncthreads();
    __threadfence();                       // release: flush gates to device
    if (tid == 0) atomicAdd(cntG, 1u);
  } else if (bid < 40) {
    // ---- pack RwT (AWBW/Vs/Vl produced before this kernel) ----
    const int n = (bid - 36) * 256 + tid;
#pragma unroll
    for (int j = 0; j < 8; j++) {
      RwT[n * 32 + j]      = f2bf(AWBW[j * DD + n]);
      RwT[n * 32 + 8 + j]  = f2bf(AWBW[(8 + j) * DD + n]);
      RwT[n * 32 + 16 + j] = f2bf(Vs[(long)j * DD + n]);
      RwT[n * 32 + 24 + j] = f2bf(Vl[(long)j * DD + n]);
    }
    __syncthreads();
    __threadfence();                       // release: flush RwT to device
    if (tid == 0) atomicAdd(cntG, 1u);
  } else {
    // ---- GEMM block ----
    const int g = bid - 40;                // dispatch XCD = g%8 (40%8==0)
    const int lane = tid & 63, w = tid >> 6;
    const int quad = lane >> 4, lrow = lane & 15;
    const int bm = (g & 7) * 16 + (g >> 6);
    const int bn = (g >> 3) & 7;
    const long m0 = (long)bm * 128;
    const int n0 = bn * 128;
    const int batch = bm >> 5;
    float* Ml = (float*)(smem + 36864);
    float* gl = (float*)(smem + 37888);
    Ml[tid] = Mbuf[tid];
    const int mw = (w & 1) * 64, nw = (w >> 1) * 64;
    const int pc0 = (w >> 1) * 16;
    const int sr = lane >> 2, sc = (lane & 3) * 16;
    const char* xbp = (const char*)xb;
    const char* wtp = (const char*)Wt;
    const char* pbp = (const char*)Pb;
    const long aOff0 = (m0 + (long)w * 16 + sr) * 2048 + sc;
    const long aOff1 = aOff0 + 4 * 16 * 2048;
    const long bOff0 = ((long)n0 + w * 16 + sr) * 2048 + sc;
    const long bOff1 = bOff0 + 4 * 16 * 2048;
    const long pOff  = ((long)w * 16 + sr) * 2048 + sc;
    const int d0 = w * 1024 + lane * 16;

    f32x4 acc[4][4] = {};
    f32x4 acc2[4] = {};

    gll16(xbp + aOff0, smem + d0);
    gll16(xbp + aOff1, smem + d0 + 4096);
    gll16(wtp + bOff0, smem + 16384 + d0);
    gll16(wtp + bOff1, smem + 16384 + d0 + 4096);
    if (w < 2) gll16(pbp + pOff, smem + 32768 + d0);
    __syncthreads();

    int cur = 0;
    for (int kc = 0; kc < 32; kc++) {
      if (kc < 31) {
        const long ko = (long)(kc + 1) * 64;
        const int sbuf = cur ^ 1;
        gll16(xbp + aOff0 + ko, smem + sbuf * 8192 + d0);
        gll16(xbp + aOff1 + ko, smem + sbuf * 8192 + d0 + 4096);
        gll16(wtp + bOff0 + ko, smem + 16384 + sbuf * 8192 + d0);
        gll16(wtp + bOff1 + ko, smem + 16384 + sbuf * 8192 + d0 + 4096);
        if (w < 2) gll16(pbp + pOff + ko, smem + 32768 + sbuf * 2048 + d0);
      }
      const u16* At = (const u16*)(smem + cur * 8192);
      const u16* Bt = (const u16*)(smem + 16384 + cur * 8192);
      const u16* Pt = (const u16*)(smem + 32768 + cur * 2048);
      bf16x8 af[4], bq[4], bp;
#pragma unroll
      for (int tm = 0; tm < 4; tm++)
        af[tm] = *(const bf16x8*)(At + (mw + tm * 16 + lrow) * 32 + quad * 8);
#pragma unroll
      for (int tn = 0; tn < 4; tn++)
        bq[tn] = *(const bf16x8*)(Bt + (nw + tn * 16 + lrow) * 32 + quad * 8);
      bp = *(const bf16x8*)(Pt + (pc0 + lrow) * 32 + quad * 8);
#pragma unroll
      for (int tm = 0; tm < 4; tm++)
#pragma unroll
        for (int tn = 0; tn < 4; tn++)
          acc[tm][tn] = __builtin_amdgcn_mfma_f32_16x16x32_bf16(af[tm], bq[tn], acc[tm][tn], 0, 0, 0);
#pragma unroll
      for (int tm = 0; tm < 4; tm++)
        acc2[tm] = __builtin_amdgcn_mfma_f32_16x16x32_bf16(af[tm], bp, acc2[tm], 0, 0, 0);
      __syncthreads();
      cur ^= 1;
    }

    // wait for conditioner outputs (normally already done ~60us ago)
    if (tid == 0) {
      while (atomicAdd(cntG, 0u) < 8u) __builtin_amdgcn_s_sleep(2);
    }
    __syncthreads();
    __threadfence();                       // acquire: invalidate stale lines
    if (tid < 24) gl[tid] = gates[batch * 32 + tid];

    // stage RwT tile into B0 region
    {
      const char* rwp = (const char*)RwT;
      const long rOff = ((long)n0 + w * 16 + sr) * 64 + sc;
      gll16(rwp + rOff, smem + 16384 + d0);
      gll16(rwp + rOff + 64 * 64, smem + 16384 + d0 + 4096);
    }
    // proj C-frags -> projF, col XOR-swizzled by (row&31)
    float* projF = (float*)smem;
#pragma unroll
    for (int tm = 0; tm < 4; tm++)
#pragma unroll
      for (int r = 0; r < 4; r++) {
        int row = mw + tm * 16 + quad * 4 + r;
        int col = pc0 + lrow;
        projF[row * 32 + (col ^ (row & 31))] = acc2[tm][r];
      }
    __syncthreads();
    if (tid < 128) {
      float pr[32];
#pragma unroll
      for (int j = 0; j < 32; j++) pr[j] = projF[tid * 32 + (j ^ (tid & 31))];
      float wo[32];
#pragma unroll
      for (int k = 0; k < 8; k++) { wo[k] = gl[k] * pr[8 + k]; wo[8 + k] = -gl[k] * pr[k]; }
#pragma unroll
      for (int kp = 0; kp < 8; kp++) {
        float sv = pr[16 + kp], tv = pr[24 + kp];
#pragma unroll
        for (int k = 0; k < 8; k++) {
          float gpb = gl[k] * pr[8 + k], gpa = gl[k] * pr[k];
          sv += gpb * Ml[k * 8 + kp]       - gpa * Ml[64 + k * 8 + kp];
          tv += gpb * Ml[128 + k * 8 + kp] - gpa * Ml[192 + k * 8 + kp];
        }
        wo[16 + kp] = gl[8 + kp] * sv;
        wo[24 + kp] = gl[16 + kp] * tv;
      }
      u16* wLds = (u16*)(smem + 24576);
#pragma unroll
      for (int j = 0; j < 32; j++) wLds[tid * 32 + j] = f2bf(wo[j]);
    }
    __syncthreads();
    {
      const u16* wL = (const u16*)(smem + 24576);
      const u16* Rt = (const u16*)(smem + 16384);
      bf16x8 af[4], bq[4];
#pragma unroll
      for (int tm = 0; tm < 4; tm++)
        af[tm] = *(const bf16x8*)(wL + (mw + tm * 16 + lrow) * 32 + quad * 8);
#pragma unroll
      for (int tn = 0; tn < 4; tn++)
        bq[tn] = *(const bf16x8*)(Rt + (nw + tn * 16 + lrow) * 32 + quad * 8);
#pragma unroll
      for (int tm = 0; tm < 4; tm++)
#pragma unroll
        for (int tn = 0; tn < 4; tn++)
          acc[tm][tn] = __builtin_amdgcn_mfma_f32_16x16x32_bf16(af[tm], bq[tn], acc[tm][tn], 0, 0, 0);
    }
#pragma unroll
    for (int tn = 0; tn < 4; tn++) {
      const int col = n0 + nw + tn * 16 + lrow;
      const float bias = bb[col];
#pragma unroll
      for (int tm = 0; tm < 4; tm++)
#pragma unroll
        for (int r = 0; r < 4; r++) {
          long row = m0 + mw + tm * 16 + quad * 4 + r;
          out[row * DD + col] = acc[tm][tn][r] + bias;
        }
    }
  }
}

// ---------------------------------------------------------------------------
// mode-B fallback: standalone conditioner kernel (old k2ab) + GEMM
// ---------------------------------------------------------------------------
__global__ __launch_bounds__(256) void k2ab(
    const float* __restrict__ pooledsum,
    const float* __restrict__ lng, const float* __restrict__ lnb,
    const float* __restrict__ Wc1, float* __restrict__ h1pre,
    const float* __restrict__ AWBW, const float* Vs, const float* Vl,
    const float* bc1, const float* Wc2, const float* bc2,
    const float* Wrg, const float* brg, const float* Wrc, const float* brc,
    const float* Wsg, const float* bsg, const float* Wlc, const float* blc,
    float* __restrict__ gates, u16* __restrict__ RwT,
    u32* __restrict__ cnt) {
  const int tid = threadIdx.x;
  if (blockIdx.x < 32) {
    __shared__ float zs[1024];
    __shared__ float red[256];
    const int b = blockIdx.x >> 3, ch = blockIdx.x & 7;
    float4 v = *(const float4*)(pooledsum + b * DD + tid * 4);
    v.x *= (1.f / 4096.f); v.y *= (1.f / 4096.f); v.z *= (1.f / 4096.f); v.w *= (1.f / 4096.f);
    float s = v.x + v.y + v.z + v.w;
    float sq = v.x * v.x + v.y * v.y + v.z * v.z + v.w * v.w;
    red[tid] = s; __syncthreads();
    for (int st = 128; st > 0; st >>= 1) { if (tid < st) red[tid] += red[tid + st]; __syncthreads(); }
    float mu = red[0] * (1.f / 1024.f);
    __syncthreads();
    red[tid] = sq; __syncthreads();
    for (int st = 128; st > 0; st >>= 1) { if (tid < st) red[tid] += red[tid + st]; __syncthreads(); }
    float var = red[0] * (1.f / 1024.f) - mu * mu;
    float rs = rsqrtf(var + 1e-5f);
    __syncthreads();
    {
      float4 g = *(const float4*)(lng + tid * 4);
      float4 be = *(const float4*)(lnb + tid * 4);
      zs[tid * 4 + 0] = (v.x - mu) * rs * g.x + be.x;
      zs[tid * 4 + 1] = (v.y - mu) * rs * g.y + be.y;
      zs[tid * 4 + 2] = (v.z - mu) * rs * g.z + be.z;
      zs[tid * 4 + 3] = (v.w - mu) * rs * g.w + be.w;
    }
    __syncthreads();
    const int j = tid & 127, half = tid >> 7;
    float a = 0.f;
#pragma unroll 8
    for (int dd = 0; dd < 64; dd++) {
      int ldi = half * 64 + dd;
      a += zs[ch * 128 + ldi] * Wc1[(long)ch * 16384 + ldi * 128 + j];
    }
    red[tid] = a;
    __syncthreads();
    if (tid < 128) atomicAdd(&h1pre[b * 128 + tid], red[tid] + red[tid + 128]);
    __syncthreads();
    if (tid == 0) atomicAdd(cnt, 1u);
  } else if (blockIdx.x < 36) {
    __shared__ float h1s[128], hb[128];
    __shared__ float red[256];
    const int b = (int)blockIdx.x - 32;
    if (tid == 0) {
      while (atomicAdd(cnt, 0u) < 32u) __builtin_amdgcn_s_sleep(8);
    }
    __syncthreads();
    if (tid < 128) {
      float hv = atomicAdd(&h1pre[b * 128 + tid], 0.f) + bc1[tid];
      float th = tanhf(0.7978845608028654f * (hv + 0.044715f * hv * hv * hv));
      h1s[tid] = 0.5f * hv * (1.f + th);
    }
    __syncthreads();
    const int i = tid & 127, half = tid >> 7;
    float a = 0.f;
#pragma unroll 8
    for (int k = 0; k < 64; k++) {
      int kk = half * 64 + k;
      a += h1s[kk] * Wc2[kk * 128 + i];
    }
    red[tid] = a;
    __syncthreads();
    if (tid < 128) hb[tid] = red[tid] + red[tid + 128] + bc2[tid];
    __syncthreads();
    if (tid < 25) {
      float acc;
      if (tid == 0) {
        acc = brg[0];
        for (int k = 0; k < 128; k++) acc += hb[k] * Wrg[k];
        red[0] = 1.f / (1.f + expf(-acc));
      } else if (tid < 9) {
        int ci = tid - 1; acc = brc[ci];
        for (int k = 0; k < 128; k++) acc += hb[k] * Wrc[k * 8 + ci];
        red[tid] = tanhf(acc);
      } else if (tid < 17) {
        int ci = tid - 9; acc = bsg[ci];
        for (int k = 0; k < 128; k++) acc += hb[k] * Wsg[k * 8 + ci];
        red[tid] = tanhf(acc);
      } else {
        int ci = tid - 17; acc = blc[ci];
        for (int k = 0; k < 128; k++) acc += hb[k] * Wlc[k * 8 + ci];
        red[tid] = tanhf(acc);
      }
    }
    __syncthreads();
    if (tid < 24) {
      float g = red[0];
      gates[b * 32 + tid] = (tid < 8) ? g * red[1 + tid] : red[1 + tid];
    }
  } else {
    const int n = (int)(blockIdx.x - 36) * 256 + tid;
#pragma unroll
    for (int j = 0; j < 8; j++) {
      RwT[n * 32 + j]      = f2bf(AWBW[j * DD + n]);
      RwT[n * 32 + 8 + j]  = f2bf(AWBW[(8 + j) * DD + n]);
      RwT[n * 32 + 16 + j] = f2bf(Vs[(long)j * DD + n]);
      RwT[n * 32 + 24 + j] = f2bf(Vl[(long)j * DD + n]);
    }
  }
}

template <bool XB>
__global__ __launch_bounds__(256) void k3_fused(
    const float* __restrict__ xf, const u16* __restrict__ xb,
    const u16* __restrict__ Wt, const u16* __restrict__ Pb,
    const float* __restrict__ gates, const float* __restrict__ Mbuf,
    const u16* __restrict__ RwT, const float* __restrict__ bb,
    float* __restrict__ out) {
  __shared__ __align__(16) u16 At[4096];
  __shared__ __align__(16) u16 Bt[4096];
  __shared__ __align__(16) u16 Pt[1024];
  __shared__ float projF[128 * 32];
  __shared__ __align__(16) u16 wLds[4096];
  __shared__ float Ml[256];
  __shared__ float gl[24];
  const int tid = threadIdx.x, lane = tid & 63, w = tid >> 6;
  const int quad = lane >> 4, lrow = lane & 15;
  const int bn = blockIdx.x & 7, bm = blockIdx.x >> 3;
  const long m0 = (long)bm * 128;
  const int n0 = bn * 128;
  const int batch = bm >> 5;
  Ml[tid] = Mbuf[tid];
  if (tid < 24) gl[tid] = gates[batch * 32 + tid];
  const int mw = (w & 1) * 64, nw = (w >> 1) * 64;
  const int p0 = (w * 2) * 1024 + lane * 16, p1 = p0 + 1024;
  f32x4 acc[4][4] = {};
  f32x4 acc2[2][2] = {};
  for (int kc = 0; kc < 32; kc++) {
    uint4 vb0 = *(const uint4*)((const char*)Wt + (long)(n0 + (p0 >> 6)) * 2048 + kc * 64 + (p0 & 63));
    uint4 vb1 = *(const uint4*)((const char*)Wt + (long)(n0 + (p1 >> 6)) * 2048 + kc * 64 + (p1 & 63));
    uint4 vp;
    if (tid < 128)
      vp = *(const uint4*)((const char*)Pb + (tid >> 2) * 2048 + kc * 64 + (tid & 3) * 16);
    if (XB) {
      uint4 va0 = *(const uint4*)((const char*)xb + (m0 + (p0 >> 6)) * 2048 + kc * 64 + (p0 & 63));
      uint4 va1 = *(const uint4*)((const char*)xb + (m0 + (p1 >> 6)) * 2048 + kc * 64 + (p1 & 63));
      *(uint4*)((char*)At + p0) = va0;
      *(uint4*)((char*)At + p1) = va1;
    } else {
      ushort4 oa[4];
#pragma unroll
      for (int i = 0; i < 4; i++) {
        int fi = i * 256 + tid, row = fi >> 3, c4 = (fi & 7) * 4;
        float4 v = *(const float4*)(xf + (m0 + row) * DD + kc * 32 + c4);
        oa[i].x = f2bf(v.x); oa[i].y = f2bf(v.y); oa[i].z = f2bf(v.z); oa[i].w = f2bf(v.w);
      }
#pragma unroll
      for (int i = 0; i < 4; i++) {
        int fi = i * 256 + tid, row = fi >> 3, c4 = (fi & 7) * 4;
        *(ushort4*)(At + row * 32 + c4) = oa[i];
      }
    }
    *(uint4*)((char*)Bt + p0) = vb0;
    *(uint4*)((char*)Bt + p1) = vb1;
    if (tid < 128) *(uint4*)((char*)Pt + (tid >> 2) * 64 + (tid & 3) * 16) = vp;
    __syncthreads();
    bf16x8 af[4], bq[4], af2[2], bp[2];
#pragma unroll
    for (int tm = 0; tm < 4; tm++)
      af[tm] = *(const bf16x8*)(At + (mw + tm * 16 + lrow) * 32 + quad * 8);
#pragma unroll
    for (int tn = 0; tn < 4; tn++)
      bq[tn] = *(const bf16x8*)(Bt + (nw + tn * 16 + lrow) * 32 + quad * 8);
#pragma unroll
    for (int t2 = 0; t2 < 2; t2++)
      af2[t2] = *(const bf16x8*)(At + (w * 32 + t2 * 16 + lrow) * 32 + quad * 8);
#pragma unroll
    for (int tn2 = 0; tn2 < 2; tn2++)
      bp[tn2] = *(const bf16x8*)(Pt + (tn2 * 16 + lrow) * 32 + quad * 8);
#pragma unroll
    for (int tm = 0; tm < 4; tm++)
#pragma unroll
      for (int tn = 0; tn < 4; tn++)
        acc[tm][tn] = __builtin_amdgcn_mfma_f32_16x16x32_bf16(af[tm], bq[tn], acc[tm][tn], 0, 0, 0);
#pragma unroll
    for (int t2 = 0; t2 < 2; t2++)
#pragma unroll
      for (int tn2 = 0; tn2 < 2; tn2++)
        acc2[t2][tn2] = __builtin_amdgcn_mfma_f32_16x16x32_bf16(af2[t2], bp[tn2], acc2[t2][tn2], 0, 0, 0);
    __syncthreads();
  }
#pragma unroll
  for (int t2 = 0; t2 < 2; t2++)
#pragma unroll
    for (int tn2 = 0; tn2 < 2; tn2++)
#pragma unroll
      for (int r = 0; r < 4; r++)
        projF[(w * 32 + t2 * 16 + quad * 4 + r) * 32 + tn2 * 16 + lrow] = acc2[t2][tn2][r];
  {
    uint4 vr0 = *(const uint4*)((const char*)RwT + (long)(n0 + (p0 >> 6)) * 64 + (p0 & 63));
    uint4 vr1 = *(const uint4*)((const char*)RwT + (long)(n0 + (p1 >> 6)) * 64 + (p1 & 63));
    *(uint4*)((char*)Bt + p0) = vr0;
    *(uint4*)((char*)Bt + p1) = vr1;
  }
  __syncthreads();
  if (tid < 128) {
    float pr[32];
#pragma unroll
    for (int j = 0; j < 32; j++) pr[j] = projF[tid * 32 + j];
    float wo[32];
#pragma unroll
    for (int k = 0; k < 8; k++) { wo[k] = gl[k] * pr[8 + k]; wo[8 + k] = -gl[k] * pr[k]; }
#pragma unroll
    for (int kp = 0; kp < 8; kp++) {
      float sv = pr[16 + kp], tv = pr[24 + kp];
#pragma unroll
      for (int k = 0; k < 8; k++) {
        float gpb = gl[k] * pr[8 + k], gpa = gl[k] * pr[k];
        sv += gpb * Ml[k * 8 + kp]       - gpa * Ml[64 + k * 8 + kp];
        tv += gpb * Ml[128 + k * 8 + kp] - gpa * Ml[192 + k * 8 + kp];
      }
      wo[16 + kp] = gl[8 + kp] * sv;
      wo[24 + kp] = gl[16 + kp] * tv;
    }
#pragma unroll
    for (int j = 0; j < 32; j++) wLds[tid * 32 + j] = f2bf(wo[j]);
  }
  __syncthreads();
  {
    bf16x8 af[4], bq[4];
#pragma unroll
    for (int tm = 0; tm < 4; tm++)
      af[tm] = *(const bf16x8*)(wLds + (mw + tm * 16 + lrow) * 32 + quad * 8);
#pragma unroll
    for (int tn = 0; tn < 4; tn++)
      bq[tn] = *(const bf16x8*)(Bt + (nw + tn * 16 + lrow) * 32 + quad * 8);
#pragma unroll
    for (int tm = 0; tm < 4; tm++)
#pragma unroll
      for (int tn = 0; tn < 4; tn++)
        acc[tm][tn] = __builtin_amdgcn_mfma_f32_16x16x32_bf16(af[tm], bq[tn], acc[tm][tn], 0, 0, 0);
  }
#pragma unroll
  for (int tn = 0; tn < 4; tn++) {
    const int col = n0 + nw + tn * 16 + lrow;
    const float bias = bb[col];
#pragma unroll
    for (int tm = 0; tm < 4; tm++)
#pragma unroll
      for (int r = 0; r < 4; r++) {
        long row = m0 + mw + tm * 16 + quad * 4 + r;
        out[row * DD + col] = acc[tm][tn][r] + bias;
      }
  }
}

// ---------------------------------------------------------------------------
extern "C" void kernel_launch(void* const* d_in, const int* in_sizes, int n_in,
                              void* d_out, int out_size, void* d_ws, size_t ws_size,
                              hipStream_t stream) {
  const float* x   = (const float*)d_in[0];
  const float* Wb  = (const float*)d_in[1];
  const float* bb  = (const float*)d_in[2];
  const float* lng = (const float*)d_in[3];
  const float* lnb = (const float*)d_in[4];
  const float* Wc1 = (const float*)d_in[5];
  const float* bc1 = (const float*)d_in[6];
  const float* Wc2 = (const float*)d_in[7];
  const float* bc2 = (const float*)d_in[8];
  const float* Wrg = (const float*)d_in[9];
  const float* brg = (const float*)d_in[10];
  const float* Wrc = (const float*)d_in[11];
  const float* brc = (const float*)d_in[12];
  const float* Wsg = (const float*)d_in[13];
  const float* bsg = (const float*)d_in[14];
  const float* Wlc = (const float*)d_in[15];
  const float* blc = (const float*)d_in[16];
  const float* Us  = (const float*)d_in[17];
  const float* Vs  = (const float*)d_in[18];
  const float* Ul  = (const float*)d_in[19];
  const float* Vl  = (const float*)d_in[20];
  const float* Ao  = (const float*)d_in[21];
  const float* Bo  = (const float*)d_in[22];

  char* ws = (char*)d_ws;
  float* pooled = (float*)(ws + 0);         //  4*1024 f32  [memset]
  float* AWBW   = (float*)(ws + 16384);     // 16*1024 f32  [memset]
  float* h1pre  = (float*)(ws + 81920);     //  4*128 f32   [memset] -> 83968
  float* gates  = (float*)(ws + 83968);     //  4*32  f32   -> 84480
  float* Mbuf   = (float*)(ws + 84480);     //  256   f32   -> 85504
  u32*   cntH   = (u32*)  (ws + 85504);     //  counter [memset]
  u32*   cntG   = (u32*)  (ws + 85508);     //  counter [memset] -> 85568
  u16*   RwT    = (u16*)  (ws + 85568);     // 1024*32 bf16 -> 151104
  u16*   Pb     = (u16*)  (ws + 151104);    // 32*1024 bf16 -> 216640
  u16*   Wt     = (u16*)  (ws + 216640);    // 1024*1024 bf16 (2 MB) -> 2313792
  u16*   xb     = (u16*)  (ws + 2313792);   // 16384*1024 bf16 (32 MB), mode A
  float* out    = (float*)d_out;

  const bool modeA = ws_size >= (size_t)2313792 + 33554432;

  (void)hipMemsetAsync(d_ws, 0, 85568, stream);   // pooled+AWBW+h1pre+cnts
  if (modeA) {
    k01_pre<true><<<1320, 256, 0, stream>>>(x, xb, pooled, Wb, Ao, Bo, Us, Ul,
                                            AWBW, Mbuf, Pb, Wt);
    k3a_mega<<<1064, 256, 0, stream>>>(xb, Wt, Pb, Mbuf, bb,
                                       pooled, lng, lnb, Wc1, h1pre,
                                       AWBW, Vs, Vl, bc1, Wc2, bc2,
                                       Wrg, brg, Wrc, brc, Wsg, bsg, Wlc, blc,
                                       gates, RwT, cntH, cntG, out);
  } else {
    k01_pre<false><<<1320, 256, 0, stream>>>(x, xb, pooled, Wb, Ao, Bo, Us, Ul,
                                             AWBW, Mbuf, Pb, Wt);
    k2ab<<<40, 256, 0, stream>>>(pooled, lng, lnb, Wc1, h1pre,
                                 AWBW, Vs, Vl, bc1, Wc2, bc2,
                                 Wrg, brg, Wrc, brc, Wsg, bsg, Wlc, blc,
                                 gates, RwT, cntH);
    k3_fused<false><<<1024, 256, 0, stream>>>(x, xb, Wt, Pb, gates, Mbuf, RwT, bb, out);
  }
}

// Round 6
// 311.375 us; speedup vs baseline: 1.2173x; 1.2173x over previous
//
#include <hip/hip_runtime.h>

typedef unsigned short u16;
typedef unsigned int   u32;
typedef __bf16 bf16x8 __attribute__((ext_vector_type(8)));
typedef float  f32x4  __attribute__((ext_vector_type(4)));

#define DD 1024

__device__ __forceinline__ u16 f2bf(float f) {
  u32 u = __float_as_uint(f);
  u32 r = (u + 0x7FFFu + ((u >> 16) & 1u)) >> 16;
  return (u16)r;
}

// async global->LDS, 16B per lane. Dest must be wave-uniform-base + lane*16.
typedef const __attribute__((address_space(1))) void* gp1;
typedef __attribute__((address_space(3))) void* lp3;
__device__ __forceinline__ void gll16(const void* g, void* l) {
  __builtin_amdgcn_global_load_lds((gp1)g, (lp3)l, 16, 0, 0);
}

// ---------------------------------------------------------------------------
// k01: merged pre-kernel. HEAVY BLOCKS FIRST (dispatch order = start order).
// blocks 0..31    : AWBW[16][1024] = {A,B}@W_base (fp32 atomics, split-i)
// blocks 32..35   : Mbuf: 4 Gram 8x8 (A.Us, B.Us, A.Ul, B.Ul)
// blocks 36..39   : Pb[32][1024] = bf16([Ao;Bo;Us;Ul])
// blocks 40..295  : Wt[n][k] = bf16(W[k][n])  (transpose + convert)
// blocks 296..1319: x fp32 -> bf16 (XB) + pooled sums, 16 rows/block,
//                   XCD row-swizzle matching k3b's reader XCD.
// ---------------------------------------------------------------------------
template <bool XB>
__global__ __launch_bounds__(256) void k01_pre(
    const float* __restrict__ x, u16* __restrict__ xb, float* __restrict__ pooled,
    const float* __restrict__ W,
    const float* __restrict__ Ao, const float* __restrict__ Bo,
    const float* __restrict__ Us, const float* __restrict__ Ul,
    float* __restrict__ AWBW, float* __restrict__ Mbuf,
    u16* __restrict__ Pb, u16* __restrict__ Wt) {
  const int tid = threadIdx.x;
  const int bid = blockIdx.x;
  if (bid >= 296) {
    const int i = bid - 296;                   // dispatch XCD = i%8 (296%8==0)
    const int xcd = i & 7, local = i >> 3;
    const int rb = xcd * 128 + local;          // row-block 0..1023
    const int b = rb >> 8;
    const long r0 = (long)rb * 16;
    const int c0 = tid * 4;
    float s0 = 0.f, s1 = 0.f, s2 = 0.f, s3 = 0.f;
    for (int r = 0; r < 16; r++) {
      float4 v = *(const float4*)(x + (r0 + r) * DD + c0);
      if (XB) {
        ushort4 o;
        o.x = f2bf(v.x); o.y = f2bf(v.y); o.z = f2bf(v.z); o.w = f2bf(v.w);
        *(ushort4*)(xb + (r0 + r) * DD + c0) = o;
      }
      s0 += v.x; s1 += v.y; s2 += v.z; s3 += v.w;
    }
    atomicAdd(&pooled[b * DD + c0 + 0], s0);
    atomicAdd(&pooled[b * DD + c0 + 1], s1);
    atomicAdd(&pooled[b * DD + c0 + 2], s2);
    atomicAdd(&pooled[b * DD + c0 + 3], s3);
    return;
  }
  if (bid < 32) {
    __shared__ float red2[2][128][16];
    const int m = bid;
    const int n = (m & 7) * 128 + (tid & 127), q = m >> 3, ih = tid >> 7;
    float acc[16];
#pragma unroll
    for (int k = 0; k < 16; k++) acc[k] = 0.f;
    const int ib = q * 256 + ih * 128;
    for (int i = ib; i < ib + 128; i++) {
      float wv = W[(long)i * DD + n];
#pragma unroll
      for (int k = 0; k < 8; k++) {
        acc[k]     += Ao[k * DD + i] * wv;
        acc[k + 8] += Bo[k * DD + i] * wv;
      }
    }
#pragma unroll
    for (int k = 0; k < 16; k++) red2[ih][tid & 127][k] = acc[k];
    __syncthreads();
    if (ih == 0)
#pragma unroll
      for (int k = 0; k < 16; k++)
        atomicAdd(&AWBW[k * DD + n], red2[0][tid][k] + red2[1][tid][k]);
  } else if (bid < 36) {
    __shared__ float red[64][4];
    const int m = bid - 32;
    const float* L  = (m == 0 || m == 2) ? Ao : Bo;
    const float* Rr = (m < 2) ? Us : Ul;
    const int o = tid >> 2, ch = tid & 3;
    const int k = o >> 3, kp = o & 7;
    float a = 0.f;
    for (int i = ch * 256; i < ch * 256 + 256; i++)
      a += L[(long)k * DD + i] * Rr[(long)kp * DD + i];
    red[o][ch] = a;
    __syncthreads();
    if (tid < 64) Mbuf[m * 64 + tid] = red[tid][0] + red[tid][1] + red[tid][2] + red[tid][3];
  } else if (bid < 40) {
    const int m = bid - 36;
    const float* src = m == 0 ? Ao : m == 1 ? Bo : m == 2 ? Us : Ul;
#pragma unroll
    for (int j = 0; j < 8; j++)
      for (int q = 0; q < 4; q++) {
        int i = q * 256 + tid;
        Pb[(m * 8 + j) * DD + i] = f2bf(src[j * DD + i]);
      }
  } else {
    __shared__ u16 T[64][66];
    const int t = bid - 40, tr = t >> 4, tc = t & 15;
#pragma unroll
    for (int q2 = 0; q2 < 16; q2++) {
      int idx = q2 * 256 + tid, r = idx >> 6, c = idx & 63;
      T[r][c] = f2bf(W[(long)(tr * 64 + r) * DD + tc * 64 + c]);
    }
    __syncthreads();
#pragma unroll
    for (int q2 = 0; q2 < 16; q2++) {
      int idx = q2 * 256 + tid, c = idx >> 6, r = idx & 63;
      Wt[(long)(tc * 64 + c) * DD + tr * 64 + r] = T[r][c];
    }
  }
}

// ---------------------------------------------------------------------------
// k2ab: conditioner chain (separate kernel — round-5 mega-merge regressed 2x).
// blocks 0..31 : h1pre partials, then signal counter.
// blocks 32..35: spin until counter==32, then gates[b][24].
// blocks 36..39: pack RwT[n][32].
// ---------------------------------------------------------------------------
__global__ __launch_bounds__(256) void k2ab(
    const float* __restrict__ pooledsum,
    const float* __restrict__ lng, const float* __restrict__ lnb,
    const float* __restrict__ Wc1, float* __restrict__ h1pre,
    const float* __restrict__ AWBW, const float* Vs, const float* Vl,
    const float* bc1, const float* Wc2, const float* bc2,
    const float* Wrg, const float* brg, const float* Wrc, const float* brc,
    const float* Wsg, const float* bsg, const float* Wlc, const float* blc,
    float* __restrict__ gates, u16* __restrict__ RwT,
    u32* __restrict__ cnt) {
  const int tid = threadIdx.x;
  if (blockIdx.x < 32) {
    __shared__ float zs[1024];
    __shared__ float red[256];
    const int b = blockIdx.x >> 3, ch = blockIdx.x & 7;
    float4 v = *(const float4*)(pooledsum + b * DD + tid * 4);
    v.x *= (1.f / 4096.f); v.y *= (1.f / 4096.f); v.z *= (1.f / 4096.f); v.w *= (1.f / 4096.f);
    float s = v.x + v.y + v.z + v.w;
    float sq = v.x * v.x + v.y * v.y + v.z * v.z + v.w * v.w;
    red[tid] = s; __syncthreads();
    for (int st = 128; st > 0; st >>= 1) { if (tid < st) red[tid] += red[tid + st]; __syncthreads(); }
    float mu = red[0] * (1.f / 1024.f);
    __syncthreads();
    red[tid] = sq; __syncthreads();
    for (int st = 128; st > 0; st >>= 1) { if (tid < st) red[tid] += red[tid + st]; __syncthreads(); }
    float var = red[0] * (1.f / 1024.f) - mu * mu;
    float rs = rsqrtf(var + 1e-5f);
    __syncthreads();
    {
      float4 g = *(const float4*)(lng + tid * 4);
      float4 be = *(const float4*)(lnb + tid * 4);
      zs[tid * 4 + 0] = (v.x - mu) * rs * g.x + be.x;
      zs[tid * 4 + 1] = (v.y - mu) * rs * g.y + be.y;
      zs[tid * 4 + 2] = (v.z - mu) * rs * g.z + be.z;
      zs[tid * 4 + 3] = (v.w - mu) * rs * g.w + be.w;
    }
    __syncthreads();
    const int j = tid & 127, half = tid >> 7;
    float a = 0.f;
#pragma unroll 8
    for (int dd = 0; dd < 64; dd++) {
      int ldi = half * 64 + dd;
      a += zs[ch * 128 + ldi] * Wc1[(long)ch * 16384 + ldi * 128 + j];
    }
    red[tid] = a;
    __syncthreads();
    if (tid < 128) atomicAdd(&h1pre[b * 128 + tid], red[tid] + red[tid + 128]);
    __syncthreads();
    if (tid == 0) atomicAdd(cnt, 1u);
  } else if (blockIdx.x < 36) {
    __shared__ float h1s[128], hb[128];
    __shared__ float red[256];
    const int b = (int)blockIdx.x - 32;
    if (tid == 0) {
      while (atomicAdd(cnt, 0u) < 32u) __builtin_amdgcn_s_sleep(8);
    }
    __syncthreads();
    if (tid < 128) {
      float hv = atomicAdd(&h1pre[b * 128 + tid], 0.f) + bc1[tid];
      float th = tanhf(0.7978845608028654f * (hv + 0.044715f * hv * hv * hv));
      h1s[tid] = 0.5f * hv * (1.f + th);
    }
    __syncthreads();
    const int i = tid & 127, half = tid >> 7;
    float a = 0.f;
#pragma unroll 8
    for (int k = 0; k < 64; k++) {
      int kk = half * 64 + k;
      a += h1s[kk] * Wc2[kk * 128 + i];
    }
    red[tid] = a;
    __syncthreads();
    if (tid < 128) hb[tid] = red[tid] + red[tid + 128] + bc2[tid];
    __syncthreads();
    if (tid < 25) {
      float acc;
      if (tid == 0) {
        acc = brg[0];
        for (int k = 0; k < 128; k++) acc += hb[k] * Wrg[k];
        red[0] = 1.f / (1.f + expf(-acc));
      } else if (tid < 9) {
        int ci = tid - 1; acc = brc[ci];
        for (int k = 0; k < 128; k++) acc += hb[k] * Wrc[k * 8 + ci];
        red[tid] = tanhf(acc);
      } else if (tid < 17) {
        int ci = tid - 9; acc = bsg[ci];
        for (int k = 0; k < 128; k++) acc += hb[k] * Wsg[k * 8 + ci];
        red[tid] = tanhf(acc);
      } else {
        int ci = tid - 17; acc = blc[ci];
        for (int k = 0; k < 128; k++) acc += hb[k] * Wlc[k * 8 + ci];
        red[tid] = tanhf(acc);
      }
    }
    __syncthreads();
    if (tid < 24) {
      float g = red[0];
      gates[b * 32 + tid] = (tid < 8) ? g * red[1 + tid] : red[1 + tid];
    }
  } else {
    const int n = (int)(blockIdx.x - 36) * 256 + tid;
#pragma unroll
    for (int j = 0; j < 8; j++) {
      RwT[n * 32 + j]      = f2bf(AWBW[j * DD + n]);
      RwT[n * 32 + 8 + j]  = f2bf(AWBW[(8 + j) * DD + n]);
      RwT[n * 32 + 16 + j] = f2bf(Vs[(long)j * DD + n]);
      RwT[n * 32 + 24 + j] = f2bf(Vl[(long)j * DD + n]);
    }
  }
}

// ---------------------------------------------------------------------------
// k3b (mode A): fused GEMM, 128x256 tile, 512 blocks @ 2 blocks/CU =
// EXACTLY one co-residency round (kills the 1024/768 dispatch tail).
// Per wave-chunk: 36 MFMA vs 13 ds_read (2x density of the 128x128 tile);
// A staged once per 256 output cols (A traffic halved).
// Double-buffered gll16, one barrier/chunk, XCD-bijective swizzle
// (xcd=g&7; 64 blocks/XCD = 16 bm-slabs x 4 bn2).
// LDS map: A0 0..8K, A1 8..16K, B0 16..32K, B1 32..48K, P0 48K..50K,
// P1 50K..52K, Ml 52K, gl 53K. Post-loop: projF->A0+A1, RwT->B0, wLds->B1.
// ---------------------------------------------------------------------------
__global__ __launch_bounds__(256, 2) void k3b_fused(
    const u16* __restrict__ xb, const u16* __restrict__ Wt,
    const u16* __restrict__ Pb, const float* __restrict__ gates,
    const float* __restrict__ Mbuf, const u16* __restrict__ RwT,
    const float* __restrict__ bb, float* __restrict__ out) {
  __shared__ __align__(16) char smem[54400];
  const int tid = threadIdx.x, lane = tid & 63, w = tid >> 6;
  const int quad = lane >> 4, lrow = lane & 15;
  const int g = blockIdx.x;
  const int xcd = g & 7, local = g >> 3;
  const int bm = xcd * 16 + (local >> 2);
  const int bn2 = local & 3;
  const long m0 = (long)bm * 128;
  const int n0 = bn2 * 256;
  const int batch = bm >> 5;
  float* Ml = (float*)(smem + 53248);
  float* gl = (float*)(smem + 54272);
  Ml[tid] = Mbuf[tid];
  if (tid < 24) gl[tid] = gates[batch * 32 + tid];
  const int mw = (w & 1) * 64, nw = (w >> 1) * 128;
  const int pc0 = (w >> 1) * 16;
  const int sr = lane >> 2, sc = (lane & 3) * 16;
  const char* xbp = (const char*)xb;
  const char* wtp = (const char*)Wt;
  const char* pbp = (const char*)Pb;
  const long aOff0 = (m0 + (long)w * 16 + sr) * 2048 + sc;
  const long aOff1 = aOff0 + 64 * 2048;
  const long bOff  = ((long)n0 + w * 16 + sr) * 2048 + sc;   // + seg*64*2048
  const long pOff  = ((long)w * 16 + sr) * 2048 + sc;        // w<2 only
  const int d0 = w * 1024 + lane * 16;

  f32x4 acc[4][8] = {};
  f32x4 acc2[4] = {};

  // prologue: stage chunk 0 into buffer 0
  gll16(xbp + aOff0, smem + d0);
  gll16(xbp + aOff1, smem + d0 + 4096);
#pragma unroll
  for (int seg = 0; seg < 4; seg++)
    gll16(wtp + bOff + (long)seg * 64 * 2048, smem + 16384 + seg * 4096 + d0);
  if (w < 2) gll16(pbp + pOff, smem + 49152 + d0);
  __syncthreads();

  int cur = 0;
  for (int kc = 0; kc < 32; kc++) {
    if (kc < 31) {                       // prefetch next chunk into cur^1
      const long ko = (long)(kc + 1) * 64;
      const int s = cur ^ 1;
      gll16(xbp + aOff0 + ko, smem + s * 8192 + d0);
      gll16(xbp + aOff1 + ko, smem + s * 8192 + d0 + 4096);
#pragma unroll
      for (int seg = 0; seg < 4; seg++)
        gll16(wtp + bOff + (long)seg * 64 * 2048 + ko,
              smem + 16384 + s * 16384 + seg * 4096 + d0);
      if (w < 2) gll16(pbp + pOff + ko, smem + 49152 + s * 2048 + d0);
    }
    const u16* At = (const u16*)(smem + cur * 8192);
    const u16* Bt = (const u16*)(smem + 16384 + cur * 16384);
    const u16* Pt = (const u16*)(smem + 49152 + cur * 2048);
    bf16x8 af[4], bq[8], bp;
#pragma unroll
    for (int tm = 0; tm < 4; tm++)
      af[tm] = *(const bf16x8*)(At + (mw + tm * 16 + lrow) * 32 + quad * 8);
#pragma unroll
    for (int tn = 0; tn < 8; tn++)
      bq[tn] = *(const bf16x8*)(Bt + (nw + tn * 16 + lrow) * 32 + quad * 8);
    bp = *(const bf16x8*)(Pt + (pc0 + lrow) * 32 + quad * 8);
#pragma unroll
    for (int tm = 0; tm < 4; tm++)
#pragma unroll
      for (int tn = 0; tn < 8; tn++)
        acc[tm][tn] = __builtin_amdgcn_mfma_f32_16x16x32_bf16(af[tm], bq[tn], acc[tm][tn], 0, 0, 0);
#pragma unroll
    for (int tm = 0; tm < 4; tm++)
      acc2[tm] = __builtin_amdgcn_mfma_f32_16x16x32_bf16(af[tm], bp, acc2[tm], 0, 0, 0);
    __syncthreads();   // drains prefetch vmcnt + publishes buffer cur^1
    cur ^= 1;
  }

  // stage RwT[n0..n0+256)[32] (16KB) into B0 region (last B0 read was kc=30)
  {
    const long rOff = ((long)n0 + w * 16 + sr) * 64 + sc;
#pragma unroll
    for (int seg = 0; seg < 4; seg++)
      gll16((const char*)RwT + rOff + (long)seg * 64 * 64,
            smem + 16384 + seg * 4096 + d0);
  }
  // proj C-frags -> projF [128][32] fp32 (overlays A0+A1), col XOR-swizzle
  float* projF = (float*)smem;
#pragma unroll
  for (int tm = 0; tm < 4; tm++)
#pragma unroll
    for (int r = 0; r < 4; r++) {
      int row = mw + tm * 16 + quad * 4 + r;
      int col = pc0 + lrow;
      projF[row * 32 + (col ^ (row & 31))] = acc2[tm][r];
    }
  __syncthreads();   // drains RwT gll16 + projF ds_writes
  // per-token 32 coefficients -> wLds (overlays B1)
  if (tid < 128) {
    float pr[32];
#pragma unroll
    for (int j = 0; j < 32; j++) pr[j] = projF[tid * 32 + (j ^ (tid & 31))];
    float wo[32];
#pragma unroll
    for (int k = 0; k < 8; k++) { wo[k] = gl[k] * pr[8 + k]; wo[8 + k] = -gl[k] * pr[k]; }
#pragma unroll
    for (int kp = 0; kp < 8; kp++) {
      float sv = pr[16 + kp], tv = pr[24 + kp];
#pragma unroll
      for (int k = 0; k < 8; k++) {
        float gpb = gl[k] * pr[8 + k], gpa = gl[k] * pr[k];
        sv += gpb * Ml[k * 8 + kp]       - gpa * Ml[64 + k * 8 + kp];
        tv += gpb * Ml[128 + k * 8 + kp] - gpa * Ml[192 + k * 8 + kp];
      }
      wo[16 + kp] = gl[8 + kp] * sv;
      wo[24 + kp] = gl[16 + kp] * tv;
    }
    u16* wLds = (u16*)(smem + 32768);
#pragma unroll
    for (int j = 0; j < 32; j++) wLds[tid * 32 + j] = f2bf(wo[j]);
  }
  __syncthreads();
  // final K-chunk: coeffs @ RwT
  {
    const u16* wL = (const u16*)(smem + 32768);
    const u16* Rt = (const u16*)(smem + 16384);
    bf16x8 af[4], bq[8];
#pragma unroll
    for (int tm = 0; tm < 4; tm++)
      af[tm] = *(const bf16x8*)(wL + (mw + tm * 16 + lrow) * 32 + quad * 8);
#pragma unroll
    for (int tn = 0; tn < 8; tn++)
      bq[tn] = *(const bf16x8*)(Rt + (nw + tn * 16 + lrow) * 32 + quad * 8);
#pragma unroll
    for (int tm = 0; tm < 4; tm++)
#pragma unroll
      for (int tn = 0; tn < 8; tn++)
        acc[tm][tn] = __builtin_amdgcn_mfma_f32_16x16x32_bf16(af[tm], bq[tn], acc[tm][tn], 0, 0, 0);
  }
  // epilogue: + bias, fp32 store
#pragma unroll
  for (int tn = 0; tn < 8; tn++) {
    const int col = n0 + nw + tn * 16 + lrow;
    const float bias = bb[col];
#pragma unroll
    for (int tm = 0; tm < 4; tm++)
#pragma unroll
      for (int r = 0; r < 4; r++) {
        long row = m0 + mw + tm * 16 + quad * 4 + r;
        out[row * DD + col] = acc[tm][tn][r] + bias;
      }
  }
}

// ---------------------------------------------------------------------------
// mode-B fallback GEMM (register-staged path, fp32 x with convert)
// ---------------------------------------------------------------------------
template <bool XB>
__global__ __launch_bounds__(256) void k3_fused(
    const float* __restrict__ xf, const u16* __restrict__ xb,
    const u16* __restrict__ Wt, const u16* __restrict__ Pb,
    const float* __restrict__ gates, const float* __restrict__ Mbuf,
    const u16* __restrict__ RwT, const float* __restrict__ bb,
    float* __restrict__ out) {
  __shared__ __align__(16) u16 At[4096];
  __shared__ __align__(16) u16 Bt[4096];
  __shared__ __align__(16) u16 Pt[1024];
  __shared__ float projF[128 * 32];
  __shared__ __align__(16) u16 wLds[4096];
  __shared__ float Ml[256];
  __shared__ float gl[24];
  const int tid = threadIdx.x, lane = tid & 63, w = tid >> 6;
  const int quad = lane >> 4, lrow = lane & 15;
  const int bn = blockIdx.x & 7, bm = blockIdx.x >> 3;
  const long m0 = (long)bm * 128;
  const int n0 = bn * 128;
  const int batch = bm >> 5;
  Ml[tid] = Mbuf[tid];
  if (tid < 24) gl[tid] = gates[batch * 32 + tid];
  const int mw = (w & 1) * 64, nw = (w >> 1) * 64;
  const int p0 = (w * 2) * 1024 + lane * 16, p1 = p0 + 1024;
  f32x4 acc[4][4] = {};
  f32x4 acc2[2][2] = {};
  for (int kc = 0; kc < 32; kc++) {
    uint4 vb0 = *(const uint4*)((const char*)Wt + (long)(n0 + (p0 >> 6)) * 2048 + kc * 64 + (p0 & 63));
    uint4 vb1 = *(const uint4*)((const char*)Wt + (long)(n0 + (p1 >> 6)) * 2048 + kc * 64 + (p1 & 63));
    uint4 vp;
    if (tid < 128)
      vp = *(const uint4*)((const char*)Pb + (tid >> 2) * 2048 + kc * 64 + (tid & 3) * 16);
    if (XB) {
      uint4 va0 = *(const uint4*)((const char*)xb + (m0 + (p0 >> 6)) * 2048 + kc * 64 + (p0 & 63));
      uint4 va1 = *(const uint4*)((const char*)xb + (m0 + (p1 >> 6)) * 2048 + kc * 64 + (p1 & 63));
      *(uint4*)((char*)At + p0) = va0;
      *(uint4*)((char*)At + p1) = va1;
    } else {
      ushort4 oa[4];
#pragma unroll
      for (int i = 0; i < 4; i++) {
        int fi = i * 256 + tid, row = fi >> 3, c4 = (fi & 7) * 4;
        float4 v = *(const float4*)(xf + (m0 + row) * DD + kc * 32 + c4);
        oa[i].x = f2bf(v.x); oa[i].y = f2bf(v.y); oa[i].z = f2bf(v.z); oa[i].w = f2bf(v.w);
      }
#pragma unroll
      for (int i = 0; i < 4; i++) {
        int fi = i * 256 + tid, row = fi >> 3, c4 = (fi & 7) * 4;
        *(ushort4*)(At + row * 32 + c4) = oa[i];
      }
    }
    *(uint4*)((char*)Bt + p0) = vb0;
    *(uint4*)((char*)Bt + p1) = vb1;
    if (tid < 128) *(uint4*)((char*)Pt + (tid >> 2) * 64 + (tid & 3) * 16) = vp;
    __syncthreads();
    bf16x8 af[4], bq[4], af2[2], bp[2];
#pragma unroll
    for (int tm = 0; tm < 4; tm++)
      af[tm] = *(const bf16x8*)(At + (mw + tm * 16 + lrow) * 32 + quad * 8);
#pragma unroll
    for (int tn = 0; tn < 4; tn++)
      bq[tn] = *(const bf16x8*)(Bt + (nw + tn * 16 + lrow) * 32 + quad * 8);
#pragma unroll
    for (int t2 = 0; t2 < 2; t2++)
      af2[t2] = *(const bf16x8*)(At + (w * 32 + t2 * 16 + lrow) * 32 + quad * 8);
#pragma unroll
    for (int tn2 = 0; tn2 < 2; tn2++)
      bp[tn2] = *(const bf16x8*)(Pt + (tn2 * 16 + lrow) * 32 + quad * 8);
#pragma unroll
    for (int tm = 0; tm < 4; tm++)
#pragma unroll
      for (int tn = 0; tn < 4; tn++)
        acc[tm][tn] = __builtin_amdgcn_mfma_f32_16x16x32_bf16(af[tm], bq[tn], acc[tm][tn], 0, 0, 0);
#pragma unroll
    for (int t2 = 0; t2 < 2; t2++)
#pragma unroll
      for (int tn2 = 0; tn2 < 2; tn2++)
        acc2[t2][tn2] = __builtin_amdgcn_mfma_f32_16x16x32_bf16(af2[t2], bp[tn2], acc2[t2][tn2], 0, 0, 0);
    __syncthreads();
  }
#pragma unroll
  for (int t2 = 0; t2 < 2; t2++)
#pragma unroll
    for (int tn2 = 0; tn2 < 2; tn2++)
#pragma unroll
      for (int r = 0; r < 4; r++)
        projF[(w * 32 + t2 * 16 + quad * 4 + r) * 32 + tn2 * 16 + lrow] = acc2[t2][tn2][r];
  {
    uint4 vr0 = *(const uint4*)((const char*)RwT + (long)(n0 + (p0 >> 6)) * 64 + (p0 & 63));
    uint4 vr1 = *(const uint4*)((const char*)RwT + (long)(n0 + (p1 >> 6)) * 64 + (p1 & 63));
    *(uint4*)((char*)Bt + p0) = vr0;
    *(uint4*)((char*)Bt + p1) = vr1;
  }
  __syncthreads();
  if (tid < 128) {
    float pr[32];
#pragma unroll
    for (int j = 0; j < 32; j++) pr[j] = projF[tid * 32 + j];
    float wo[32];
#pragma unroll
    for (int k = 0; k < 8; k++) { wo[k] = gl[k] * pr[8 + k]; wo[8 + k] = -gl[k] * pr[k]; }
#pragma unroll
    for (int kp = 0; kp < 8; kp++) {
      float sv = pr[16 + kp], tv = pr[24 + kp];
#pragma unroll
      for (int k = 0; k < 8; k++) {
        float gpb = gl[k] * pr[8 + k], gpa = gl[k] * pr[k];
        sv += gpb * Ml[k * 8 + kp]       - gpa * Ml[64 + k * 8 + kp];
        tv += gpb * Ml[128 + k * 8 + kp] - gpa * Ml[192 + k * 8 + kp];
      }
      wo[16 + kp] = gl[8 + kp] * sv;
      wo[24 + kp] = gl[16 + kp] * tv;
    }
#pragma unroll
    for (int j = 0; j < 32; j++) wLds[tid * 32 + j] = f2bf(wo[j]);
  }
  __syncthreads();
  {
    bf16x8 af[4], bq[4];
#pragma unroll
    for (int tm = 0; tm < 4; tm++)
      af[tm] = *(const bf16x8*)(wLds + (mw + tm * 16 + lrow) * 32 + quad * 8);
#pragma unroll
    for (int tn = 0; tn < 4; tn++)
      bq[tn] = *(const bf16x8*)(Bt + (nw + tn * 16 + lrow) * 32 + quad * 8);
#pragma unroll
    for (int tm = 0; tm < 4; tm++)
#pragma unroll
      for (int tn = 0; tn < 4; tn++)
        acc[tm][tn] = __builtin_amdgcn_mfma_f32_16x16x32_bf16(af[tm], bq[tn], acc[tm][tn], 0, 0, 0);
  }
#pragma unroll
  for (int tn = 0; tn < 4; tn++) {
    const int col = n0 + nw + tn * 16 + lrow;
    const float bias = bb[col];
#pragma unroll
    for (int tm = 0; tm < 4; tm++)
#pragma unroll
      for (int r = 0; r < 4; r++) {
        long row = m0 + mw + tm * 16 + quad * 4 + r;
        out[row * DD + col] = acc[tm][tn][r] + bias;
      }
  }
}

// ---------------------------------------------------------------------------
extern "C" void kernel_launch(void* const* d_in, const int* in_sizes, int n_in,
                              void* d_out, int out_size, void* d_ws, size_t ws_size,
                              hipStream_t stream) {
  const float* x   = (const float*)d_in[0];
  const float* Wb  = (const float*)d_in[1];
  const float* bb  = (const float*)d_in[2];
  const float* lng = (const float*)d_in[3];
  const float* lnb = (const float*)d_in[4];
  const float* Wc1 = (const float*)d_in[5];
  const float* bc1 = (const float*)d_in[6];
  const float* Wc2 = (const float*)d_in[7];
  const float* bc2 = (const float*)d_in[8];
  const float* Wrg = (const float*)d_in[9];
  const float* brg = (const float*)d_in[10];
  const float* Wrc = (const float*)d_in[11];
  const float* brc = (const float*)d_in[12];
  const float* Wsg = (const float*)d_in[13];
  const float* bsg = (const float*)d_in[14];
  const float* Wlc = (const float*)d_in[15];
  const float* blc = (const float*)d_in[16];
  const float* Us  = (const float*)d_in[17];
  const float* Vs  = (const float*)d_in[18];
  const float* Ul  = (const float*)d_in[19];
  const float* Vl  = (const float*)d_in[20];
  const float* Ao  = (const float*)d_in[21];
  const float* Bo  = (const float*)d_in[22];

  char* ws = (char*)d_ws;
  float* pooled = (float*)(ws + 0);         //  4*1024 f32  [memset]
  float* AWBW   = (float*)(ws + 16384);     // 16*1024 f32  [memset]
  float* h1pre  = (float*)(ws + 81920);     //  4*128 f32   [memset] -> 83968
  float* gates  = (float*)(ws + 83968);     //  4*32  f32   -> 84480
  float* Mbuf   = (float*)(ws + 84480);     //  256   f32   -> 85504
  u32*   cntH   = (u32*)  (ws + 85504);     //  counter [memset] -> 85568
  u16*   RwT    = (u16*)  (ws + 85568);     // 1024*32 bf16 -> 151104
  u16*   Pb     = (u16*)  (ws + 151104);    // 32*1024 bf16 -> 216640
  u16*   Wt     = (u16*)  (ws + 216640);    // 1024*1024 bf16 (2 MB) -> 2313792
  u16*   xb     = (u16*)  (ws + 2313792);   // 16384*1024 bf16 (32 MB), mode A
  float* out    = (float*)d_out;

  const bool modeA = ws_size >= (size_t)2313792 + 33554432;

  (void)hipMemsetAsync(d_ws, 0, 85568, stream);   // pooled+AWBW+h1pre+cnt
  if (modeA) {
    k01_pre<true><<<1320, 256, 0, stream>>>(x, xb, pooled, Wb, Ao, Bo, Us, Ul,
                                            AWBW, Mbuf, Pb, Wt);
    k2ab<<<40, 256, 0, stream>>>(pooled, lng, lnb, Wc1, h1pre,
                                 AWBW, Vs, Vl, bc1, Wc2, bc2,
                                 Wrg, brg, Wrc, brc, Wsg, bsg, Wlc, blc,
                                 gates, RwT, cntH);
    k3b_fused<<<512, 256, 0, stream>>>(xb, Wt, Pb, gates, Mbuf, RwT, bb, out);
  } else {
    k01_pre<false><<<1320, 256, 0, stream>>>(x, xb, pooled, Wb, Ao, Bo, Us, Ul,
                                             AWBW, Mbuf, Pb, Wt);
    k2ab<<<40, 256, 0, stream>>>(pooled, lng, lnb, Wc1, h1pre,
                                 AWBW, Vs, Vl, bc1, Wc2, bc2,
                                 Wrg, brg, Wrc, brc, Wsg, bsg, Wlc, blc,
                                 gates, RwT, cntH);
    k3_fused<false><<<1024, 256, 0, stream>>>(x, xb, Wt, Pb, gates, Mbuf, RwT, bb, out);
  }
}

// Round 7
// 295.455 us; speedup vs baseline: 1.2828x; 1.0539x over previous
//
#include <hip/hip_runtime.h>

typedef unsigned short u16;
typedef unsigned int   u32;
typedef __bf16 bf16x8 __attribute__((ext_vector_type(8)));
typedef float  f32x4  __attribute__((ext_vector_type(4)));

#define DD 1024

__device__ __forceinline__ u16 f2bf(float f) {
  u32 u = __float_as_uint(f);
  u32 r = (u + 0x7FFFu + ((u >> 16) & 1u)) >> 16;
  return (u16)r;
}

// async global->LDS, 16B per lane. Dest must be wave-uniform-base + lane*16.
typedef const __attribute__((address_space(1))) void* gp1;
typedef __attribute__((address_space(3))) void* lp3;
__device__ __forceinline__ void gll16(const void* g, void* l) {
  __builtin_amdgcn_global_load_lds((gp1)g, (lp3)l, 16, 0, 0);
}

// ---------------------------------------------------------------------------
// k01: merged pre-kernel. Heavy blocks first; shared arrays UNION'd into one
// 16 KB blob so streamer blocks aren't LDS-capped (was 26 KB -> 6 blocks/CU;
// now 16.4 KB -> 9 blocks/CU).
// blocks 0..31  : AWBW[16][1024] = {A,B}@W_base (fp32 atomics, split-i)
// blocks 32..35 : Mbuf: 4 Gram 8x8 (A.Us, B.Us, A.Ul, B.Ul)
// blocks 36..39 : Pb[32][1024] = bf16([Ao;Bo;Us;Ul])
// blocks 40..295: Wt[n][k] = bf16(W[k][n])  (transpose + convert)
// blocks 296..807: x fp32 -> bf16 (XB) + pooled sums. 512 blocks x 32 rows,
//   16-deep load batching (all 16 float4 in flight before converts/stores),
//   XCD row-swizzle matching k3b's reader XCD, half the atomic count.
// ---------------------------------------------------------------------------
template <bool XB>
__global__ __launch_bounds__(256) void k01_pre(
    const float* __restrict__ x, u16* __restrict__ xb, float* __restrict__ pooled,
    const float* __restrict__ W,
    const float* __restrict__ Ao, const float* __restrict__ Bo,
    const float* __restrict__ Us, const float* __restrict__ Ul,
    float* __restrict__ AWBW, float* __restrict__ Mbuf,
    u16* __restrict__ Pb, u16* __restrict__ Wt) {
  __shared__ __align__(16) char shb[16384];   // union: red2 | red | T
  const int tid = threadIdx.x;
  const int bid = blockIdx.x;
  if (bid >= 296) {
    const int i = bid - 296;                   // dispatch XCD = i%8 (296%8==0)
    const int xcd = i & 7, local = i >> 3;     // local 0..63
    const int rb = xcd * 64 + local;           // row-block 0..511 (32 rows ea)
    const int b = rb >> 7;                     // batch (128 rb per batch)
    const long r0 = (long)rb * 32;
    const int c0 = tid * 4;
    float s0 = 0.f, s1 = 0.f, s2 = 0.f, s3 = 0.f;
#pragma unroll
    for (int g2 = 0; g2 < 2; g2++) {
      float4 v[16];
#pragma unroll
      for (int r = 0; r < 16; r++)
        v[r] = *(const float4*)(x + (r0 + g2 * 16 + r) * DD + c0);
#pragma unroll
      for (int r = 0; r < 16; r++) {
        if (XB) {
          ushort4 o;
          o.x = f2bf(v[r].x); o.y = f2bf(v[r].y);
          o.z = f2bf(v[r].z); o.w = f2bf(v[r].w);
          *(ushort4*)(xb + (r0 + g2 * 16 + r) * DD + c0) = o;
        }
        s0 += v[r].x; s1 += v[r].y; s2 += v[r].z; s3 += v[r].w;
      }
    }
    atomicAdd(&pooled[b * DD + c0 + 0], s0);
    atomicAdd(&pooled[b * DD + c0 + 1], s1);
    atomicAdd(&pooled[b * DD + c0 + 2], s2);
    atomicAdd(&pooled[b * DD + c0 + 3], s3);
    return;
  }
  if (bid < 32) {
    float (*red2)[128][16] = (float (*)[128][16])shb;   // 16384 B
    const int m = bid;
    const int n = (m & 7) * 128 + (tid & 127), q = m >> 3, ih = tid >> 7;
    float acc[16];
#pragma unroll
    for (int k = 0; k < 16; k++) acc[k] = 0.f;
    const int ib = q * 256 + ih * 128;
    for (int i = ib; i < ib + 128; i++) {
      float wv = W[(long)i * DD + n];
#pragma unroll
      for (int k = 0; k < 8; k++) {
        acc[k]     += Ao[k * DD + i] * wv;
        acc[k + 8] += Bo[k * DD + i] * wv;
      }
    }
#pragma unroll
    for (int k = 0; k < 16; k++) red2[ih][tid & 127][k] = acc[k];
    __syncthreads();
    if (ih == 0)
#pragma unroll
      for (int k = 0; k < 16; k++)
        atomicAdd(&AWBW[k * DD + n], red2[0][tid][k] + red2[1][tid][k]);
  } else if (bid < 36) {
    float (*red)[4] = (float (*)[4])shb;                // 1024 B
    const int m = bid - 32;
    const float* L  = (m == 0 || m == 2) ? Ao : Bo;
    const float* Rr = (m < 2) ? Us : Ul;
    const int o = tid >> 2, ch = tid & 3;
    const int k = o >> 3, kp = o & 7;
    float a = 0.f;
    for (int i = ch * 256; i < ch * 256 + 256; i++)
      a += L[(long)k * DD + i] * Rr[(long)kp * DD + i];
    red[o][ch] = a;
    __syncthreads();
    if (tid < 64) Mbuf[m * 64 + tid] = red[tid][0] + red[tid][1] + red[tid][2] + red[tid][3];
  } else if (bid < 40) {
    const int m = bid - 36;
    const float* src = m == 0 ? Ao : m == 1 ? Bo : m == 2 ? Us : Ul;
#pragma unroll
    for (int j = 0; j < 8; j++)
      for (int q = 0; q < 4; q++) {
        int i = q * 256 + tid;
        Pb[(m * 8 + j) * DD + i] = f2bf(src[j * DD + i]);
      }
  } else {
    u16 (*T)[66] = (u16 (*)[66])shb;                    // 8448 B
    const int t = bid - 40, tr = t >> 4, tc = t & 15;
#pragma unroll
    for (int q2 = 0; q2 < 16; q2++) {
      int idx = q2 * 256 + tid, r = idx >> 6, c = idx & 63;
      T[r][c] = f2bf(W[(long)(tr * 64 + r) * DD + tc * 64 + c]);
    }
    __syncthreads();
#pragma unroll
    for (int q2 = 0; q2 < 16; q2++) {
      int idx = q2 * 256 + tid, c = idx >> 6, r = idx & 63;
      Wt[(long)(tc * 64 + c) * DD + tr * 64 + r] = T[r][c];
    }
  }
}

// ---------------------------------------------------------------------------
// k2ab: conditioner chain.
// blocks 0..31 : h1pre partials, then signal counter.
// blocks 32..35: spin until counter==32, then gates[b][24].
// blocks 36..39: pack RwT[n][32].
// ---------------------------------------------------------------------------
__global__ __launch_bounds__(256) void k2ab(
    const float* __restrict__ pooledsum,
    const float* __restrict__ lng, const float* __restrict__ lnb,
    const float* __restrict__ Wc1, float* __restrict__ h1pre,
    const float* __restrict__ AWBW, const float* Vs, const float* Vl,
    const float* bc1, const float* Wc2, const float* bc2,
    const float* Wrg, const float* brg, const float* Wrc, const float* brc,
    const float* Wsg, const float* bsg, const float* Wlc, const float* blc,
    float* __restrict__ gates, u16* __restrict__ RwT,
    u32* __restrict__ cnt) {
  const int tid = threadIdx.x;
  if (blockIdx.x < 32) {
    __shared__ float zs[1024];
    __shared__ float red[256];
    const int b = blockIdx.x >> 3, ch = blockIdx.x & 7;
    float4 v = *(const float4*)(pooledsum + b * DD + tid * 4);
    v.x *= (1.f / 4096.f); v.y *= (1.f / 4096.f); v.z *= (1.f / 4096.f); v.w *= (1.f / 4096.f);
    float s = v.x + v.y + v.z + v.w;
    float sq = v.x * v.x + v.y * v.y + v.z * v.z + v.w * v.w;
    red[tid] = s; __syncthreads();
    for (int st = 128; st > 0; st >>= 1) { if (tid < st) red[tid] += red[tid + st]; __syncthreads(); }
    float mu = red[0] * (1.f / 1024.f);
    __syncthreads();
    red[tid] = sq; __syncthreads();
    for (int st = 128; st > 0; st >>= 1) { if (tid < st) red[tid] += red[tid + st]; __syncthreads(); }
    float var = red[0] * (1.f / 1024.f) - mu * mu;
    float rs = rsqrtf(var + 1e-5f);
    __syncthreads();
    {
      float4 g = *(const float4*)(lng + tid * 4);
      float4 be = *(const float4*)(lnb + tid * 4);
      zs[tid * 4 + 0] = (v.x - mu) * rs * g.x + be.x;
      zs[tid * 4 + 1] = (v.y - mu) * rs * g.y + be.y;
      zs[tid * 4 + 2] = (v.z - mu) * rs * g.z + be.z;
      zs[tid * 4 + 3] = (v.w - mu) * rs * g.w + be.w;
    }
    __syncthreads();
    const int j = tid & 127, half = tid >> 7;
    float a = 0.f;
#pragma unroll 8
    for (int dd = 0; dd < 64; dd++) {
      int ldi = half * 64 + dd;
      a += zs[ch * 128 + ldi] * Wc1[(long)ch * 16384 + ldi * 128 + j];
    }
    red[tid] = a;
    __syncthreads();
    if (tid < 128) atomicAdd(&h1pre[b * 128 + tid], red[tid] + red[tid + 128]);
    __syncthreads();
    if (tid == 0) atomicAdd(cnt, 1u);
  } else if (blockIdx.x < 36) {
    __shared__ float h1s[128], hb[128];
    __shared__ float red[256];
    const int b = (int)blockIdx.x - 32;
    if (tid == 0) {
      while (atomicAdd(cnt, 0u) < 32u) __builtin_amdgcn_s_sleep(8);
    }
    __syncthreads();
    if (tid < 128) {
      float hv = atomicAdd(&h1pre[b * 128 + tid], 0.f) + bc1[tid];
      float th = tanhf(0.7978845608028654f * (hv + 0.044715f * hv * hv * hv));
      h1s[tid] = 0.5f * hv * (1.f + th);
    }
    __syncthreads();
    const int i = tid & 127, half = tid >> 7;
    float a = 0.f;
#pragma unroll 8
    for (int k = 0; k < 64; k++) {
      int kk = half * 64 + k;
      a += h1s[kk] * Wc2[kk * 128 + i];
    }
    red[tid] = a;
    __syncthreads();
    if (tid < 128) hb[tid] = red[tid] + red[tid + 128] + bc2[tid];
    __syncthreads();
    if (tid < 25) {
      float acc;
      if (tid == 0) {
        acc = brg[0];
        for (int k = 0; k < 128; k++) acc += hb[k] * Wrg[k];
        red[0] = 1.f / (1.f + expf(-acc));
      } else if (tid < 9) {
        int ci = tid - 1; acc = brc[ci];
        for (int k = 0; k < 128; k++) acc += hb[k] * Wrc[k * 8 + ci];
        red[tid] = tanhf(acc);
      } else if (tid < 17) {
        int ci = tid - 9; acc = bsg[ci];
        for (int k = 0; k < 128; k++) acc += hb[k] * Wsg[k * 8 + ci];
        red[tid] = tanhf(acc);
      } else {
        int ci = tid - 17; acc = blc[ci];
        for (int k = 0; k < 128; k++) acc += hb[k] * Wlc[k * 8 + ci];
        red[tid] = tanhf(acc);
      }
    }
    __syncthreads();
    if (tid < 24) {
      float g = red[0];
      gates[b * 32 + tid] = (tid < 8) ? g * red[1 + tid] : red[1 + tid];
    }
  } else {
    const int n = (int)(blockIdx.x - 36) * 256 + tid;
#pragma unroll
    for (int j = 0; j < 8; j++) {
      RwT[n * 32 + j]      = f2bf(AWBW[j * DD + n]);
      RwT[n * 32 + 8 + j]  = f2bf(AWBW[(8 + j) * DD + n]);
      RwT[n * 32 + 16 + j] = f2bf(Vs[(long)j * DD + n]);
      RwT[n * 32 + 24 + j] = f2bf(Vl[(long)j * DD + n]);
    }
  }
}

// ---------------------------------------------------------------------------
// k3b (mode A): fused GEMM, 128x256 tile, 512 blocks @ 2 blocks/CU =
// exactly one co-residency round. Double-buffered gll16, one barrier/chunk,
// XCD-bijective swizzle. (unchanged from round 6 — it improved there)
// ---------------------------------------------------------------------------
__global__ __launch_bounds__(256, 2) void k3b_fused(
    const u16* __restrict__ xb, const u16* __restrict__ Wt,
    const u16* __restrict__ Pb, const float* __restrict__ gates,
    const float* __restrict__ Mbuf, const u16* __restrict__ RwT,
    const float* __restrict__ bb, float* __restrict__ out) {
  __shared__ __align__(16) char smem[54400];
  const int tid = threadIdx.x, lane = tid & 63, w = tid >> 6;
  const int quad = lane >> 4, lrow = lane & 15;
  const int g = blockIdx.x;
  const int xcd = g & 7, local = g >> 3;
  const int bm = xcd * 16 + (local >> 2);
  const int bn2 = local & 3;
  const long m0 = (long)bm * 128;
  const int n0 = bn2 * 256;
  const int batch = bm >> 5;
  float* Ml = (float*)(smem + 53248);
  float* gl = (float*)(smem + 54272);
  Ml[tid] = Mbuf[tid];
  if (tid < 24) gl[tid] = gates[batch * 32 + tid];
  const int mw = (w & 1) * 64, nw = (w >> 1) * 128;
  const int pc0 = (w >> 1) * 16;
  const int sr = lane >> 2, sc = (lane & 3) * 16;
  const char* xbp = (const char*)xb;
  const char* wtp = (const char*)Wt;
  const char* pbp = (const char*)Pb;
  const long aOff0 = (m0 + (long)w * 16 + sr) * 2048 + sc;
  const long aOff1 = aOff0 + 64 * 2048;
  const long bOff  = ((long)n0 + w * 16 + sr) * 2048 + sc;   // + seg*64*2048
  const long pOff  = ((long)w * 16 + sr) * 2048 + sc;        // w<2 only
  const int d0 = w * 1024 + lane * 16;

  f32x4 acc[4][8] = {};
  f32x4 acc2[4] = {};

  // prologue: stage chunk 0 into buffer 0
  gll16(xbp + aOff0, smem + d0);
  gll16(xbp + aOff1, smem + d0 + 4096);
#pragma unroll
  for (int seg = 0; seg < 4; seg++)
    gll16(wtp + bOff + (long)seg * 64 * 2048, smem + 16384 + seg * 4096 + d0);
  if (w < 2) gll16(pbp + pOff, smem + 49152 + d0);
  __syncthreads();

  int cur = 0;
  for (int kc = 0; kc < 32; kc++) {
    if (kc < 31) {                       // prefetch next chunk into cur^1
      const long ko = (long)(kc + 1) * 64;
      const int s = cur ^ 1;
      gll16(xbp + aOff0 + ko, smem + s * 8192 + d0);
      gll16(xbp + aOff1 + ko, smem + s * 8192 + d0 + 4096);
#pragma unroll
      for (int seg = 0; seg < 4; seg++)
        gll16(wtp + bOff + (long)seg * 64 * 2048 + ko,
              smem + 16384 + s * 16384 + seg * 4096 + d0);
      if (w < 2) gll16(pbp + pOff + ko, smem + 49152 + s * 2048 + d0);
    }
    const u16* At = (const u16*)(smem + cur * 8192);
    const u16* Bt = (const u16*)(smem + 16384 + cur * 16384);
    const u16* Pt = (const u16*)(smem + 49152 + cur * 2048);
    bf16x8 af[4], bq[8], bp;
#pragma unroll
    for (int tm = 0; tm < 4; tm++)
      af[tm] = *(const bf16x8*)(At + (mw + tm * 16 + lrow) * 32 + quad * 8);
#pragma unroll
    for (int tn = 0; tn < 8; tn++)
      bq[tn] = *(const bf16x8*)(Bt + (nw + tn * 16 + lrow) * 32 + quad * 8);
    bp = *(const bf16x8*)(Pt + (pc0 + lrow) * 32 + quad * 8);
#pragma unroll
    for (int tm = 0; tm < 4; tm++)
#pragma unroll
      for (int tn = 0; tn < 8; tn++)
        acc[tm][tn] = __builtin_amdgcn_mfma_f32_16x16x32_bf16(af[tm], bq[tn], acc[tm][tn], 0, 0, 0);
#pragma unroll
    for (int tm = 0; tm < 4; tm++)
      acc2[tm] = __builtin_amdgcn_mfma_f32_16x16x32_bf16(af[tm], bp, acc2[tm], 0, 0, 0);
    __syncthreads();   // drains prefetch vmcnt + publishes buffer cur^1
    cur ^= 1;
  }

  // stage RwT[n0..n0+256)[32] (16KB) into B0 region
  {
    const long rOff = ((long)n0 + w * 16 + sr) * 64 + sc;
#pragma unroll
    for (int seg = 0; seg < 4; seg++)
      gll16((const char*)RwT + rOff + (long)seg * 64 * 64,
            smem + 16384 + seg * 4096 + d0);
  }
  // proj C-frags -> projF [128][32] fp32 (overlays A0+A1), col XOR-swizzle
  float* projF = (float*)smem;
#pragma unroll
  for (int tm = 0; tm < 4; tm++)
#pragma unroll
    for (int r = 0; r < 4; r++) {
      int row = mw + tm * 16 + quad * 4 + r;
      int col = pc0 + lrow;
      projF[row * 32 + (col ^ (row & 31))] = acc2[tm][r];
    }
  __syncthreads();   // drains RwT gll16 + projF ds_writes
  // per-token 32 coefficients -> wLds (overlays B1)
  if (tid < 128) {
    float pr[32];
#pragma unroll
    for (int j = 0; j < 32; j++) pr[j] = projF[tid * 32 + (j ^ (tid & 31))];
    float wo[32];
#pragma unroll
    for (int k = 0; k < 8; k++) { wo[k] = gl[k] * pr[8 + k]; wo[8 + k] = -gl[k] * pr[k]; }
#pragma unroll
    for (int kp = 0; kp < 8; kp++) {
      float sv = pr[16 + kp], tv = pr[24 + kp];
#pragma unroll
      for (int k = 0; k < 8; k++) {
        float gpb = gl[k] * pr[8 + k], gpa = gl[k] * pr[k];
        sv += gpb * Ml[k * 8 + kp]       - gpa * Ml[64 + k * 8 + kp];
        tv += gpb * Ml[128 + k * 8 + kp] - gpa * Ml[192 + k * 8 + kp];
      }
      wo[16 + kp] = gl[8 + kp] * sv;
      wo[24 + kp] = gl[16 + kp] * tv;
    }
    u16* wLds = (u16*)(smem + 32768);
#pragma unroll
    for (int j = 0; j < 32; j++) wLds[tid * 32 + j] = f2bf(wo[j]);
  }
  __syncthreads();
  // final K-chunk: coeffs @ RwT
  {
    const u16* wL = (const u16*)(smem + 32768);
    const u16* Rt = (const u16*)(smem + 16384);
    bf16x8 af[4], bq[8];
#pragma unroll
    for (int tm = 0; tm < 4; tm++)
      af[tm] = *(const bf16x8*)(wL + (mw + tm * 16 + lrow) * 32 + quad * 8);
#pragma unroll
    for (int tn = 0; tn < 8; tn++)
      bq[tn] = *(const bf16x8*)(Rt + (nw + tn * 16 + lrow) * 32 + quad * 8);
#pragma unroll
    for (int tm = 0; tm < 4; tm++)
#pragma unroll
      for (int tn = 0; tn < 8; tn++)
        acc[tm][tn] = __builtin_amdgcn_mfma_f32_16x16x32_bf16(af[tm], bq[tn], acc[tm][tn], 0, 0, 0);
  }
  // epilogue: + bias, fp32 store
#pragma unroll
  for (int tn = 0; tn < 8; tn++) {
    const int col = n0 + nw + tn * 16 + lrow;
    const float bias = bb[col];
#pragma unroll
    for (int tm = 0; tm < 4; tm++)
#pragma unroll
      for (int r = 0; r < 4; r++) {
        long row = m0 + mw + tm * 16 + quad * 4 + r;
        out[row * DD + col] = acc[tm][tn][r] + bias;
      }
  }
}

// ---------------------------------------------------------------------------
// mode-B fallback GEMM (register-staged path, fp32 x with convert)
// ---------------------------------------------------------------------------
template <bool XB>
__global__ __launch_bounds__(256) void k3_fused(
    const float* __restrict__ xf, const u16* __restrict__ xb,
    const u16* __restrict__ Wt, const u16* __restrict__ Pb,
    const float* __restrict__ gates, const float* __restrict__ Mbuf,
    const u16* __restrict__ RwT, const float* __restrict__ bb,
    float* __restrict__ out) {
  __shared__ __align__(16) u16 At[4096];
  __shared__ __align__(16) u16 Bt[4096];
  __shared__ __align__(16) u16 Pt[1024];
  __shared__ float projF[128 * 32];
  __shared__ __align__(16) u16 wLds[4096];
  __shared__ float Ml[256];
  __shared__ float gl[24];
  const int tid = threadIdx.x, lane = tid & 63, w = tid >> 6;
  const int quad = lane >> 4, lrow = lane & 15;
  const int bn = blockIdx.x & 7, bm = blockIdx.x >> 3;
  const long m0 = (long)bm * 128;
  const int n0 = bn * 128;
  const int batch = bm >> 5;
  Ml[tid] = Mbuf[tid];
  if (tid < 24) gl[tid] = gates[batch * 32 + tid];
  const int mw = (w & 1) * 64, nw = (w >> 1) * 64;
  const int p0 = (w * 2) * 1024 + lane * 16, p1 = p0 + 1024;
  f32x4 acc[4][4] = {};
  f32x4 acc2[2][2] = {};
  for (int kc = 0; kc < 32; kc++) {
    uint4 vb0 = *(const uint4*)((const char*)Wt + (long)(n0 + (p0 >> 6)) * 2048 + kc * 64 + (p0 & 63));
    uint4 vb1 = *(const uint4*)((const char*)Wt + (long)(n0 + (p1 >> 6)) * 2048 + kc * 64 + (p1 & 63));
    uint4 vp;
    if (tid < 128)
      vp = *(const uint4*)((const char*)Pb + (tid >> 2) * 2048 + kc * 64 + (tid & 3) * 16);
    if (XB) {
      uint4 va0 = *(const uint4*)((const char*)xb + (m0 + (p0 >> 6)) * 2048 + kc * 64 + (p0 & 63));
      uint4 va1 = *(const uint4*)((const char*)xb + (m0 + (p1 >> 6)) * 2048 + kc * 64 + (p1 & 63));
      *(uint4*)((char*)At + p0) = va0;
      *(uint4*)((char*)At + p1) = va1;
    } else {
      ushort4 oa[4];
#pragma unroll
      for (int i = 0; i < 4; i++) {
        int fi = i * 256 + tid, row = fi >> 3, c4 = (fi & 7) * 4;
        float4 v = *(const float4*)(xf + (m0 + row) * DD + kc * 32 + c4);
        oa[i].x = f2bf(v.x); oa[i].y = f2bf(v.y); oa[i].z = f2bf(v.z); oa[i].w = f2bf(v.w);
      }
#pragma unroll
      for (int i = 0; i < 4; i++) {
        int fi = i * 256 + tid, row = fi >> 3, c4 = (fi & 7) * 4;
        *(ushort4*)(At + row * 32 + c4) = oa[i];
      }
    }
    *(uint4*)((char*)Bt + p0) = vb0;
    *(uint4*)((char*)Bt + p1) = vb1;
    if (tid < 128) *(uint4*)((char*)Pt + (tid >> 2) * 64 + (tid & 3) * 16) = vp;
    __syncthreads();
    bf16x8 af[4], bq[4], af2[2], bp[2];
#pragma unroll
    for (int tm = 0; tm < 4; tm++)
      af[tm] = *(const bf16x8*)(At + (mw + tm * 16 + lrow) * 32 + quad * 8);
#pragma unroll
    for (int tn = 0; tn < 4; tn++)
      bq[tn] = *(const bf16x8*)(Bt + (nw + tn * 16 + lrow) * 32 + quad * 8);
#pragma unroll
    for (int t2 = 0; t2 < 2; t2++)
      af2[t2] = *(const bf16x8*)(At + (w * 32 + t2 * 16 + lrow) * 32 + quad * 8);
#pragma unroll
    for (int tn2 = 0; tn2 < 2; tn2++)
      bp[tn2] = *(const bf16x8*)(Pt + (tn2 * 16 + lrow) * 32 + quad * 8);
#pragma unroll
    for (int tm = 0; tm < 4; tm++)
#pragma unroll
      for (int tn = 0; tn < 4; tn++)
        acc[tm][tn] = __builtin_amdgcn_mfma_f32_16x16x32_bf16(af[tm], bq[tn], acc[tm][tn], 0, 0, 0);
#pragma unroll
    for (int t2 = 0; t2 < 2; t2++)
#pragma unroll
      for (int tn2 = 0; tn2 < 2; tn2++)
        acc2[t2][tn2] = __builtin_amdgcn_mfma_f32_16x16x32_bf16(af2[t2], bp[tn2], acc2[t2][tn2], 0, 0, 0);
    __syncthreads();
  }
#pragma unroll
  for (int t2 = 0; t2 < 2; t2++)
#pragma unroll
    for (int tn2 = 0; tn2 < 2; tn2++)
#pragma unroll
      for (int r = 0; r < 4; r++)
        projF[(w * 32 + t2 * 16 + quad * 4 + r) * 32 + tn2 * 16 + lrow] = acc2[t2][tn2][r];
  {
    uint4 vr0 = *(const uint4*)((const char*)RwT + (long)(n0 + (p0 >> 6)) * 64 + (p0 & 63));
    uint4 vr1 = *(const uint4*)((const char*)RwT + (long)(n0 + (p1 >> 6)) * 64 + (p1 & 63));
    *(uint4*)((char*)Bt + p0) = vr0;
    *(uint4*)((char*)Bt + p1) = vr1;
  }
  __syncthreads();
  if (tid < 128) {
    float pr[32];
#pragma unroll
    for (int j = 0; j < 32; j++) pr[j] = projF[tid * 32 + j];
    float wo[32];
#pragma unroll
    for (int k = 0; k < 8; k++) { wo[k] = gl[k] * pr[8 + k]; wo[8 + k] = -gl[k] * pr[k]; }
#pragma unroll
    for (int kp = 0; kp < 8; kp++) {
      float sv = pr[16 + kp], tv = pr[24 + kp];
#pragma unroll
      for (int k = 0; k < 8; k++) {
        float gpb = gl[k] * pr[8 + k], gpa = gl[k] * pr[k];
        sv += gpb * Ml[k * 8 + kp]       - gpa * Ml[64 + k * 8 + kp];
        tv += gpb * Ml[128 + k * 8 + kp] - gpa * Ml[192 + k * 8 + kp];
      }
      wo[16 + kp] = gl[8 + kp] * sv;
      wo[24 + kp] = gl[16 + kp] * tv;
    }
#pragma unroll
    for (int j = 0; j < 32; j++) wLds[tid * 32 + j] = f2bf(wo[j]);
  }
  __syncthreads();
  {
    bf16x8 af[4], bq[4];
#pragma unroll
    for (int tm = 0; tm < 4; tm++)
      af[tm] = *(const bf16x8*)(wLds + (mw + tm * 16 + lrow) * 32 + quad * 8);
#pragma unroll
    for (int tn = 0; tn < 4; tn++)
      bq[tn] = *(const bf16x8*)(Bt + (nw + tn * 16 + lrow) * 32 + quad * 8);
#pragma unroll
    for (int tm = 0; tm < 4; tm++)
#pragma unroll
      for (int tn = 0; tn < 4; tn++)
        acc[tm][tn] = __builtin_amdgcn_mfma_f32_16x16x32_bf16(af[tm], bq[tn], acc[tm][tn], 0, 0, 0);
  }
#pragma unroll
  for (int tn = 0; tn < 4; tn++) {
    const int col = n0 + nw + tn * 16 + lrow;
    const float bias = bb[col];
#pragma unroll
    for (int tm = 0; tm < 4; tm++)
#pragma unroll
      for (int r = 0; r < 4; r++) {
        long row = m0 + mw + tm * 16 + quad * 4 + r;
        out[row * DD + col] = acc[tm][tn][r] + bias;
      }
  }
}

// ---------------------------------------------------------------------------
extern "C" void kernel_launch(void* const* d_in, const int* in_sizes, int n_in,
                              void* d_out, int out_size, void* d_ws, size_t ws_size,
                              hipStream_t stream) {
  const float* x   = (const float*)d_in[0];
  const float* Wb  = (const float*)d_in[1];
  const float* bb  = (const float*)d_in[2];
  const float* lng = (const float*)d_in[3];
  const float* lnb = (const float*)d_in[4];
  const float* Wc1 = (const float*)d_in[5];
  const float* bc1 = (const float*)d_in[6];
  const float* Wc2 = (const float*)d_in[7];
  const float* bc2 = (const float*)d_in[8];
  const float* Wrg = (const float*)d_in[9];
  const float* brg = (const float*)d_in[10];
  const float* Wrc = (const float*)d_in[11];
  const float* brc = (const float*)d_in[12];
  const float* Wsg = (const float*)d_in[13];
  const float* bsg = (const float*)d_in[14];
  const float* Wlc = (const float*)d_in[15];
  const float* blc = (const float*)d_in[16];
  const float* Us  = (const float*)d_in[17];
  const float* Vs  = (const float*)d_in[18];
  const float* Ul  = (const float*)d_in[19];
  const float* Vl  = (const float*)d_in[20];
  const float* Ao  = (const float*)d_in[21];
  const float* Bo  = (const float*)d_in[22];

  char* ws = (char*)d_ws;
  float* pooled = (float*)(ws + 0);         //  4*1024 f32  [memset]
  float* AWBW   = (float*)(ws + 16384);     // 16*1024 f32  [memset]
  float* h1pre  = (float*)(ws + 81920);     //  4*128 f32   [memset] -> 83968
  float* gates  = (float*)(ws + 83968);     //  4*32  f32   -> 84480
  float* Mbuf   = (float*)(ws + 84480);     //  256   f32   -> 85504
  u32*   cntH   = (u32*)  (ws + 85504);     //  counter [memset] -> 85568
  u16*   RwT    = (u16*)  (ws + 85568);     // 1024*32 bf16 -> 151104
  u16*   Pb     = (u16*)  (ws + 151104);    // 32*1024 bf16 -> 216640
  u16*   Wt     = (u16*)  (ws + 216640);    // 1024*1024 bf16 (2 MB) -> 2313792
  u16*   xb     = (u16*)  (ws + 2313792);   // 16384*1024 bf16 (32 MB), mode A
  float* out    = (float*)d_out;

  const bool modeA = ws_size >= (size_t)2313792 + 33554432;

  (void)hipMemsetAsync(d_ws, 0, 85568, stream);   // pooled+AWBW+h1pre+cnt
  if (modeA) {
    k01_pre<true><<<808, 256, 0, stream>>>(x, xb, pooled, Wb, Ao, Bo, Us, Ul,
                                           AWBW, Mbuf, Pb, Wt);
    k2ab<<<40, 256, 0, stream>>>(pooled, lng, lnb, Wc1, h1pre,
                                 AWBW, Vs, Vl, bc1, Wc2, bc2,
                                 Wrg, brg, Wrc, brc, Wsg, bsg, Wlc, blc,
                                 gates, RwT, cntH);
    k3b_fused<<<512, 256, 0, stream>>>(xb, Wt, Pb, gates, Mbuf, RwT, bb, out);
  } else {
    k01_pre<false><<<808, 256, 0, stream>>>(x, xb, pooled, Wb, Ao, Bo, Us, Ul,
                                            AWBW, Mbuf, Pb, Wt);
    k2ab<<<40, 256, 0, stream>>>(pooled, lng, lnb, Wc1, h1pre,
                                 AWBW, Vs, Vl, bc1, Wc2, bc2,
                                 Wrg, brg, Wrc, brc, Wsg, bsg, Wlc, blc,
                                 gates, RwT, cntH);
    k3_fused<false><<<1024, 256, 0, stream>>>(x, xb, Wt, Pb, gates, Mbuf, RwT, bb, out);
  }
}

// Round 8
// 279.388 us; speedup vs baseline: 1.3566x; 1.0575x over previous
//
#include <hip/hip_runtime.h>

typedef unsigned short u16;
typedef unsigned int   u32;
typedef __bf16 bf16x8 __attribute__((ext_vector_type(8)));
typedef float  f32x4  __attribute__((ext_vector_type(4)));

#define DD 1024

__device__ __forceinline__ u16 f2bf(float f) {
  u32 u = __float_as_uint(f);
  u32 r = (u + 0x7FFFu + ((u >> 16) & 1u)) >> 16;
  return (u16)r;
}

// async global->LDS, 16B per lane. Dest must be wave-uniform-base + lane*16.
typedef const __attribute__((address_space(1))) void* gp1;
typedef __attribute__((address_space(3))) void* lp3;
__device__ __forceinline__ void gll16(const void* g, void* l) {
  __builtin_amdgcn_global_load_lds((gp1)g, (lp3)l, 16, 0, 0);
}

// ---------------------------------------------------------------------------
// k01m: fully-merged pre-kernel (k01 + conditioner chain).
// blocks 0..63   : AWBW[16][1024] = {A,B}@W_base (64 blocks, 64-iter serial
//                  chain — halved from 32-block version); signal cntW.
// blocks 64..67  : Mbuf: 4 Gram 8x8.
// blocks 68..71  : Pb[32][1024] = bf16([Ao;Bo;Us;Ul]).
// blocks 72..327 : Wt[n][k] = bf16(W[k][n]) transpose.
// blocks 328..839: x fp32 -> bf16 (XB) + pooled sums; 512 blocks x 32 rows,
//                  asm-pinned 8-deep f32x4 load batches (forces MLP; round-7
//                  compiler re-rolled the batch — VGPR_Count=32 proved it);
//                  XCD row-swizzle matching k3b; signal cntS.
// blocks 840..871: LN + z@Wc1 partial (spin cntS==512; pooled via atomic
//                  reads) -> h1pre atomics; signal cntH.
// blocks 872..875: gates[b] (spin cntH==32; h1pre via atomic reads).
// blocks 876..879: pack RwT (spin cntW==64; AWBW via atomic reads).
// All 880 blocks co-resident (16.4KB LDS, <=64 VGPR -> 8 blocks/CU cap is
// the binder, 880 < 2048) -> spins deadlock-free. Producers drain their
// atomics with __syncthreads() before signaling (proven pattern, r3-r7).
// ---------------------------------------------------------------------------
template <bool XB>
__global__ __launch_bounds__(256) void k01m(
    const float* __restrict__ x, u16* __restrict__ xb, float* __restrict__ pooled,
    const float* __restrict__ W,
    const float* __restrict__ Ao, const float* __restrict__ Bo,
    const float* __restrict__ Us, const float* __restrict__ Ul,
    float* __restrict__ AWBW, float* __restrict__ Mbuf,
    u16* __restrict__ Pb, u16* __restrict__ Wt,
    const float* __restrict__ lng, const float* __restrict__ lnb,
    const float* __restrict__ Wc1, float* __restrict__ h1pre,
    const float* Vs, const float* Vl,
    const float* bc1, const float* Wc2, const float* bc2,
    const float* Wrg, const float* brg, const float* Wrc, const float* brc,
    const float* Wsg, const float* bsg, const float* Wlc, const float* blc,
    float* __restrict__ gates, u16* __restrict__ RwT,
    u32* __restrict__ cntS, u32* __restrict__ cntH, u32* __restrict__ cntW) {
  __shared__ __align__(16) char shb[16384];   // union across branches
  const int tid = threadIdx.x;
  const int bid = blockIdx.x;

  if (bid >= 328 && bid < 840) {
    // ---- streamer: convert + pooled sums ----
    const int i = bid - 328;                   // dispatch XCD = i%8 (328%8==0)
    const int xcd = i & 7, local = i >> 3;     // local 0..63
    const int rb = xcd * 64 + local;           // row-block 0..511 (32 rows ea)
    const int b = rb >> 7;
    const long r0 = (long)rb * 32;
    const int c0 = tid * 4;
    float s0 = 0.f, s1 = 0.f, s2 = 0.f, s3 = 0.f;
#pragma unroll
    for (int g2 = 0; g2 < 4; g2++) {
      f32x4 v[8];
#pragma unroll
      for (int r = 0; r < 8; r++)
        v[r] = *(const f32x4*)(x + (r0 + g2 * 8 + r) * DD + c0);
      // pin all 8 loads live -> 8-deep MLP per wave (rule: compiler re-rolls
      // plain batches; VGPR=32 in round 7 proved no ILP materialized)
      asm volatile("" : "+v"(v[0]), "+v"(v[1]), "+v"(v[2]), "+v"(v[3]),
                        "+v"(v[4]), "+v"(v[5]), "+v"(v[6]), "+v"(v[7]));
#pragma unroll
      for (int r = 0; r < 8; r++) {
        if (XB) {
          ushort4 o;
          o.x = f2bf(v[r][0]); o.y = f2bf(v[r][1]);
          o.z = f2bf(v[r][2]); o.w = f2bf(v[r][3]);
          *(ushort4*)(xb + (r0 + g2 * 8 + r) * DD + c0) = o;
        }
        s0 += v[r][0]; s1 += v[r][1]; s2 += v[r][2]; s3 += v[r][3];
      }
    }
    atomicAdd(&pooled[b * DD + c0 + 0], s0);
    atomicAdd(&pooled[b * DD + c0 + 1], s1);
    atomicAdd(&pooled[b * DD + c0 + 2], s2);
    atomicAdd(&pooled[b * DD + c0 + 3], s3);
    __syncthreads();                           // drain atomics (vmcnt 0)
    if (tid == 0) atomicAdd(cntS, 1u);
    return;
  }
  if (bid < 64) {
    // ---- AWBW: 64 blocks, 64-iteration serial chain ----
    float (*red2)[128][16] = (float (*)[128][16])shb;   // 16384 B
    const int m = bid;
    const int n = (m & 7) * 128 + (tid & 127), q = m >> 3, ih = tid >> 7;
    float acc[16];
#pragma unroll
    for (int k = 0; k < 16; k++) acc[k] = 0.f;
    const int ib = q * 128 + ih * 64;
    for (int i = ib; i < ib + 64; i++) {
      float wv = W[(long)i * DD + n];
#pragma unroll
      for (int k = 0; k < 8; k++) {
        acc[k]     += Ao[k * DD + i] * wv;
        acc[k + 8] += Bo[k * DD + i] * wv;
      }
    }
#pragma unroll
    for (int k = 0; k < 16; k++) red2[ih][tid & 127][k] = acc[k];
    __syncthreads();
    if (ih == 0)
#pragma unroll
      for (int k = 0; k < 16; k++)
        atomicAdd(&AWBW[k * DD + n], red2[0][tid][k] + red2[1][tid][k]);
    __syncthreads();                           // drain atomics
    if (tid == 0) atomicAdd(cntW, 1u);
  } else if (bid < 68) {
    float (*red)[4] = (float (*)[4])shb;                // 1024 B
    const int m = bid - 64;
    const float* L  = (m == 0 || m == 2) ? Ao : Bo;
    const float* Rr = (m < 2) ? Us : Ul;
    const int o = tid >> 2, ch = tid & 3;
    const int k = o >> 3, kp = o & 7;
    float a = 0.f;
    for (int i = ch * 256; i < ch * 256 + 256; i++)
      a += L[(long)k * DD + i] * Rr[(long)kp * DD + i];
    red[o][ch] = a;
    __syncthreads();
    if (tid < 64) Mbuf[m * 64 + tid] = red[tid][0] + red[tid][1] + red[tid][2] + red[tid][3];
  } else if (bid < 72) {
    const int m = bid - 68;
    const float* src = m == 0 ? Ao : m == 1 ? Bo : m == 2 ? Us : Ul;
#pragma unroll
    for (int j = 0; j < 8; j++)
      for (int q = 0; q < 4; q++) {
        int i = q * 256 + tid;
        Pb[(m * 8 + j) * DD + i] = f2bf(src[j * DD + i]);
      }
  } else if (bid < 328) {
    u16 (*T)[66] = (u16 (*)[66])shb;                    // 8448 B
    const int t = bid - 72, tr = t >> 4, tc = t & 15;
#pragma unroll
    for (int q2 = 0; q2 < 16; q2++) {
      int idx = q2 * 256 + tid, r = idx >> 6, c = idx & 63;
      T[r][c] = f2bf(W[(long)(tr * 64 + r) * DD + tc * 64 + c]);
    }
    __syncthreads();
#pragma unroll
    for (int q2 = 0; q2 < 16; q2++) {
      int idx = q2 * 256 + tid, c = idx >> 6, r = idx & 63;
      Wt[(long)(tc * 64 + c) * DD + tr * 64 + r] = T[r][c];
    }
  } else if (bid < 872) {
    // ---- LN + z@Wc1 partial (spin on streamers) ----
    float* zs  = (float*)shb;                  // 1024 f32
    float* red = (float*)(shb + 4096);         // 256 f32
    const int lb = bid - 840;
    const int b = lb >> 3, ch = lb & 7;
    if (tid == 0) {
      while (atomicAdd(cntS, 0u) < 512u) __builtin_amdgcn_s_sleep(8);
    }
    __syncthreads();
    float4 v;
    v.x = atomicAdd(&pooled[b * DD + tid * 4 + 0], 0.f);   // coherent reads
    v.y = atomicAdd(&pooled[b * DD + tid * 4 + 1], 0.f);
    v.z = atomicAdd(&pooled[b * DD + tid * 4 + 2], 0.f);
    v.w = atomicAdd(&pooled[b * DD + tid * 4 + 3], 0.f);
    v.x *= (1.f / 4096.f); v.y *= (1.f / 4096.f); v.z *= (1.f / 4096.f); v.w *= (1.f / 4096.f);
    float s = v.x + v.y + v.z + v.w;
    float sq = v.x * v.x + v.y * v.y + v.z * v.z + v.w * v.w;
    red[tid] = s; __syncthreads();
    for (int st = 128; st > 0; st >>= 1) { if (tid < st) red[tid] += red[tid + st]; __syncthreads(); }
    float mu = red[0] * (1.f / 1024.f);
    __syncthreads();
    red[tid] = sq; __syncthreads();
    for (int st = 128; st > 0; st >>= 1) { if (tid < st) red[tid] += red[tid + st]; __syncthreads(); }
    float var = red[0] * (1.f / 1024.f) - mu * mu;
    float rs = rsqrtf(var + 1e-5f);
    __syncthreads();
    {
      float4 g = *(const float4*)(lng + tid * 4);
      float4 be = *(const float4*)(lnb + tid * 4);
      zs[tid * 4 + 0] = (v.x - mu) * rs * g.x + be.x;
      zs[tid * 4 + 1] = (v.y - mu) * rs * g.y + be.y;
      zs[tid * 4 + 2] = (v.z - mu) * rs * g.z + be.z;
      zs[tid * 4 + 3] = (v.w - mu) * rs * g.w + be.w;
    }
    __syncthreads();
    const int j = tid & 127, half = tid >> 7;
    float a = 0.f;
#pragma unroll 8
    for (int dd = 0; dd < 64; dd++) {
      int ldi = half * 64 + dd;
      a += zs[ch * 128 + ldi] * Wc1[(long)ch * 16384 + ldi * 128 + j];
    }
    red[tid] = a;
    __syncthreads();
    if (tid < 128) atomicAdd(&h1pre[b * 128 + tid], red[tid] + red[tid + 128]);
    __syncthreads();
    if (tid == 0) atomicAdd(cntH, 1u);
  } else if (bid < 876) {
    // ---- gates for batch b (spin on LN) ----
    float* h1s = (float*)shb;
    float* hb  = (float*)(shb + 512);
    float* red = (float*)(shb + 1024);
    const int b = bid - 872;
    if (tid == 0) {
      while (atomicAdd(cntH, 0u) < 32u) __builtin_amdgcn_s_sleep(8);
    }
    __syncthreads();
    if (tid < 128) {
      float hv = atomicAdd(&h1pre[b * 128 + tid], 0.f) + bc1[tid];
      float th = tanhf(0.7978845608028654f * (hv + 0.044715f * hv * hv * hv));
      h1s[tid] = 0.5f * hv * (1.f + th);
    }
    __syncthreads();
    const int i = tid & 127, half = tid >> 7;
    float a = 0.f;
#pragma unroll 8
    for (int k = 0; k < 64; k++) {
      int kk = half * 64 + k;
      a += h1s[kk] * Wc2[kk * 128 + i];
    }
    red[tid] = a;
    __syncthreads();
    if (tid < 128) hb[tid] = red[tid] + red[tid + 128] + bc2[tid];
    __syncthreads();
    if (tid < 25) {
      float acc;
      if (tid == 0) {
        acc = brg[0];
        for (int k = 0; k < 128; k++) acc += hb[k] * Wrg[k];
        red[0] = 1.f / (1.f + expf(-acc));
      } else if (tid < 9) {
        int ci = tid - 1; acc = brc[ci];
        for (int k = 0; k < 128; k++) acc += hb[k] * Wrc[k * 8 + ci];
        red[tid] = tanhf(acc);
      } else if (tid < 17) {
        int ci = tid - 9; acc = bsg[ci];
        for (int k = 0; k < 128; k++) acc += hb[k] * Wsg[k * 8 + ci];
        red[tid] = tanhf(acc);
      } else {
        int ci = tid - 17; acc = blc[ci];
        for (int k = 0; k < 128; k++) acc += hb[k] * Wlc[k * 8 + ci];
        red[tid] = tanhf(acc);
      }
    }
    __syncthreads();
    if (tid < 24) {
      float g = red[0];
      gates[b * 32 + tid] = (tid < 8) ? g * red[1 + tid] : red[1 + tid];
    }
  } else {
    // ---- pack RwT (spin on AWBW) ----
    if (tid == 0) {
      while (atomicAdd(cntW, 0u) < 64u) __builtin_amdgcn_s_sleep(8);
    }
    __syncthreads();
    const int n = (int)(bid - 876) * 256 + tid;
#pragma unroll
    for (int j = 0; j < 8; j++) {
      RwT[n * 32 + j]      = f2bf(atomicAdd(&AWBW[j * DD + n], 0.f));
      RwT[n * 32 + 8 + j]  = f2bf(atomicAdd(&AWBW[(8 + j) * DD + n], 0.f));
      RwT[n * 32 + 16 + j] = f2bf(Vs[(long)j * DD + n]);
      RwT[n * 32 + 24 + j] = f2bf(Vl[(long)j * DD + n]);
    }
  }
}

// ---------------------------------------------------------------------------
// k3b (mode A): fused GEMM, 128x256 tile, 512 blocks @ 2 blocks/CU.
// Double-buffered gll16, one barrier/chunk, XCD-bijective swizzle.
// (unchanged from round 6/7 — steady-state dropped out of top-5)
// ---------------------------------------------------------------------------
__global__ __launch_bounds__(256, 2) void k3b_fused(
    const u16* __restrict__ xb, const u16* __restrict__ Wt,
    const u16* __restrict__ Pb, const float* __restrict__ gates,
    const float* __restrict__ Mbuf, const u16* __restrict__ RwT,
    const float* __restrict__ bb, float* __restrict__ out) {
  __shared__ __align__(16) char smem[54400];
  const int tid = threadIdx.x, lane = tid & 63, w = tid >> 6;
  const int quad = lane >> 4, lrow = lane & 15;
  const int g = blockIdx.x;
  const int xcd = g & 7, local = g >> 3;
  const int bm = xcd * 16 + (local >> 2);
  const int bn2 = local & 3;
  const long m0 = (long)bm * 128;
  const int n0 = bn2 * 256;
  const int batch = bm >> 5;
  float* Ml = (float*)(smem + 53248);
  float* gl = (float*)(smem + 54272);
  Ml[tid] = Mbuf[tid];
  if (tid < 24) gl[tid] = gates[batch * 32 + tid];
  const int mw = (w & 1) * 64, nw = (w >> 1) * 128;
  const int pc0 = (w >> 1) * 16;
  const int sr = lane >> 2, sc = (lane & 3) * 16;
  const char* xbp = (const char*)xb;
  const char* wtp = (const char*)Wt;
  const char* pbp = (const char*)Pb;
  const long aOff0 = (m0 + (long)w * 16 + sr) * 2048 + sc;
  const long aOff1 = aOff0 + 64 * 2048;
  const long bOff  = ((long)n0 + w * 16 + sr) * 2048 + sc;
  const long pOff  = ((long)w * 16 + sr) * 2048 + sc;
  const int d0 = w * 1024 + lane * 16;

  f32x4 acc[4][8] = {};
  f32x4 acc2[4] = {};

  gll16(xbp + aOff0, smem + d0);
  gll16(xbp + aOff1, smem + d0 + 4096);
#pragma unroll
  for (int seg = 0; seg < 4; seg++)
    gll16(wtp + bOff + (long)seg * 64 * 2048, smem + 16384 + seg * 4096 + d0);
  if (w < 2) gll16(pbp + pOff, smem + 49152 + d0);
  __syncthreads();

  int cur = 0;
  for (int kc = 0; kc < 32; kc++) {
    if (kc < 31) {
      const long ko = (long)(kc + 1) * 64;
      const int s = cur ^ 1;
      gll16(xbp + aOff0 + ko, smem + s * 8192 + d0);
      gll16(xbp + aOff1 + ko, smem + s * 8192 + d0 + 4096);
#pragma unroll
      for (int seg = 0; seg < 4; seg++)
        gll16(wtp + bOff + (long)seg * 64 * 2048 + ko,
              smem + 16384 + s * 16384 + seg * 4096 + d0);
      if (w < 2) gll16(pbp + pOff + ko, smem + 49152 + s * 2048 + d0);
    }
    const u16* At = (const u16*)(smem + cur * 8192);
    const u16* Bt = (const u16*)(smem + 16384 + cur * 16384);
    const u16* Pt = (const u16*)(smem + 49152 + cur * 2048);
    bf16x8 af[4], bq[8], bp;
#pragma unroll
    for (int tm = 0; tm < 4; tm++)
      af[tm] = *(const bf16x8*)(At + (mw + tm * 16 + lrow) * 32 + quad * 8);
#pragma unroll
    for (int tn = 0; tn < 8; tn++)
      bq[tn] = *(const bf16x8*)(Bt + (nw + tn * 16 + lrow) * 32 + quad * 8);
    bp = *(const bf16x8*)(Pt + (pc0 + lrow) * 32 + quad * 8);
#pragma unroll
    for (int tm = 0; tm < 4; tm++)
#pragma unroll
      for (int tn = 0; tn < 8; tn++)
        acc[tm][tn] = __builtin_amdgcn_mfma_f32_16x16x32_bf16(af[tm], bq[tn], acc[tm][tn], 0, 0, 0);
#pragma unroll
    for (int tm = 0; tm < 4; tm++)
      acc2[tm] = __builtin_amdgcn_mfma_f32_16x16x32_bf16(af[tm], bp, acc2[tm], 0, 0, 0);
    __syncthreads();
    cur ^= 1;
  }

  {
    const long rOff = ((long)n0 + w * 16 + sr) * 64 + sc;
#pragma unroll
    for (int seg = 0; seg < 4; seg++)
      gll16((const char*)RwT + rOff + (long)seg * 64 * 64,
            smem + 16384 + seg * 4096 + d0);
  }
  float* projF = (float*)smem;
#pragma unroll
  for (int tm = 0; tm < 4; tm++)
#pragma unroll
    for (int r = 0; r < 4; r++) {
      int row = mw + tm * 16 + quad * 4 + r;
      int col = pc0 + lrow;
      projF[row * 32 + (col ^ (row & 31))] = acc2[tm][r];
    }
  __syncthreads();
  if (tid < 128) {
    float pr[32];
#pragma unroll
    for (int j = 0; j < 32; j++) pr[j] = projF[tid * 32 + (j ^ (tid & 31))];
    float wo[32];
#pragma unroll
    for (int k = 0; k < 8; k++) { wo[k] = gl[k] * pr[8 + k]; wo[8 + k] = -gl[k] * pr[k]; }
#pragma unroll
    for (int kp = 0; kp < 8; kp++) {
      float sv = pr[16 + kp], tv = pr[24 + kp];
#pragma unroll
      for (int k = 0; k < 8; k++) {
        float gpb = gl[k] * pr[8 + k], gpa = gl[k] * pr[k];
        sv += gpb * Ml[k * 8 + kp]       - gpa * Ml[64 + k * 8 + kp];
        tv += gpb * Ml[128 + k * 8 + kp] - gpa * Ml[192 + k * 8 + kp];
      }
      wo[16 + kp] = gl[8 + kp] * sv;
      wo[24 + kp] = gl[16 + kp] * tv;
    }
    u16* wLds = (u16*)(smem + 32768);
#pragma unroll
    for (int j = 0; j < 32; j++) wLds[tid * 32 + j] = f2bf(wo[j]);
  }
  __syncthreads();
  {
    const u16* wL = (const u16*)(smem + 32768);
    const u16* Rt = (const u16*)(smem + 16384);
    bf16x8 af[4], bq[8];
#pragma unroll
    for (int tm = 0; tm < 4; tm++)
      af[tm] = *(const bf16x8*)(wL + (mw + tm * 16 + lrow) * 32 + quad * 8);
#pragma unroll
    for (int tn = 0; tn < 8; tn++)
      bq[tn] = *(const bf16x8*)(Rt + (nw + tn * 16 + lrow) * 32 + quad * 8);
#pragma unroll
    for (int tm = 0; tm < 4; tm++)
#pragma unroll
      for (int tn = 0; tn < 8; tn++)
        acc[tm][tn] = __builtin_amdgcn_mfma_f32_16x16x32_bf16(af[tm], bq[tn], acc[tm][tn], 0, 0, 0);
  }
#pragma unroll
  for (int tn = 0; tn < 8; tn++) {
    const int col = n0 + nw + tn * 16 + lrow;
    const float bias = bb[col];
#pragma unroll
    for (int tm = 0; tm < 4; tm++)
#pragma unroll
      for (int r = 0; r < 4; r++) {
        long row = m0 + mw + tm * 16 + quad * 4 + r;
        out[row * DD + col] = acc[tm][tn][r] + bias;
      }
  }
}

// ---------------------------------------------------------------------------
// mode-B fallback GEMM (register-staged path, fp32 x with convert)
// ---------------------------------------------------------------------------
template <bool XB>
__global__ __launch_bounds__(256) void k3_fused(
    const float* __restrict__ xf, const u16* __restrict__ xb,
    const u16* __restrict__ Wt, const u16* __restrict__ Pb,
    const float* __restrict__ gates, const float* __restrict__ Mbuf,
    const u16* __restrict__ RwT, const float* __restrict__ bb,
    float* __restrict__ out) {
  __shared__ __align__(16) u16 At[4096];
  __shared__ __align__(16) u16 Bt[4096];
  __shared__ __align__(16) u16 Pt[1024];
  __shared__ float projF[128 * 32];
  __shared__ __align__(16) u16 wLds[4096];
  __shared__ float Ml[256];
  __shared__ float gl[24];
  const int tid = threadIdx.x, lane = tid & 63, w = tid >> 6;
  const int quad = lane >> 4, lrow = lane & 15;
  const int bn = blockIdx.x & 7, bm = blockIdx.x >> 3;
  const long m0 = (long)bm * 128;
  const int n0 = bn * 128;
  const int batch = bm >> 5;
  Ml[tid] = Mbuf[tid];
  if (tid < 24) gl[tid] = gates[batch * 32 + tid];
  const int mw = (w & 1) * 64, nw = (w >> 1) * 64;
  const int p0 = (w * 2) * 1024 + lane * 16, p1 = p0 + 1024;
  f32x4 acc[4][4] = {};
  f32x4 acc2[2][2] = {};
  for (int kc = 0; kc < 32; kc++) {
    uint4 vb0 = *(const uint4*)((const char*)Wt + (long)(n0 + (p0 >> 6)) * 2048 + kc * 64 + (p0 & 63));
    uint4 vb1 = *(const uint4*)((const char*)Wt + (long)(n0 + (p1 >> 6)) * 2048 + kc * 64 + (p1 & 63));
    uint4 vp;
    if (tid < 128)
      vp = *(const uint4*)((const char*)Pb + (tid >> 2) * 2048 + kc * 64 + (tid & 3) * 16);
    if (XB) {
      uint4 va0 = *(const uint4*)((const char*)xb + (m0 + (p0 >> 6)) * 2048 + kc * 64 + (p0 & 63));
      uint4 va1 = *(const uint4*)((const char*)xb + (m0 + (p1 >> 6)) * 2048 + kc * 64 + (p1 & 63));
      *(uint4*)((char*)At + p0) = va0;
      *(uint4*)((char*)At + p1) = va1;
    } else {
      ushort4 oa[4];
#pragma unroll
      for (int i = 0; i < 4; i++) {
        int fi = i * 256 + tid, row = fi >> 3, c4 = (fi & 7) * 4;
        float4 v = *(const float4*)(xf + (m0 + row) * DD + kc * 32 + c4);
        oa[i].x = f2bf(v.x); oa[i].y = f2bf(v.y); oa[i].z = f2bf(v.z); oa[i].w = f2bf(v.w);
      }
#pragma unroll
      for (int i = 0; i < 4; i++) {
        int fi = i * 256 + tid, row = fi >> 3, c4 = (fi & 7) * 4;
        *(ushort4*)(At + row * 32 + c4) = oa[i];
      }
    }
    *(uint4*)((char*)Bt + p0) = vb0;
    *(uint4*)((char*)Bt + p1) = vb1;
    if (tid < 128) *(uint4*)((char*)Pt + (tid >> 2) * 64 + (tid & 3) * 16) = vp;
    __syncthreads();
    bf16x8 af[4], bq[4], af2[2], bp[2];
#pragma unroll
    for (int tm = 0; tm < 4; tm++)
      af[tm] = *(const bf16x8*)(At + (mw + tm * 16 + lrow) * 32 + quad * 8);
#pragma unroll
    for (int tn = 0; tn < 4; tn++)
      bq[tn] = *(const bf16x8*)(Bt + (nw + tn * 16 + lrow) * 32 + quad * 8);
#pragma unroll
    for (int t2 = 0; t2 < 2; t2++)
      af2[t2] = *(const bf16x8*)(At + (w * 32 + t2 * 16 + lrow) * 32 + quad * 8);
#pragma unroll
    for (int tn2 = 0; tn2 < 2; tn2++)
      bp[tn2] = *(const bf16x8*)(Pt + (tn2 * 16 + lrow) * 32 + quad * 8);
#pragma unroll
    for (int tm = 0; tm < 4; tm++)
#pragma unroll
      for (int tn = 0; tn < 4; tn++)
        acc[tm][tn] = __builtin_amdgcn_mfma_f32_16x16x32_bf16(af[tm], bq[tn], acc[tm][tn], 0, 0, 0);
#pragma unroll
    for (int t2 = 0; t2 < 2; t2++)
#pragma unroll
      for (int tn2 = 0; tn2 < 2; tn2++)
        acc2[t2][tn2] = __builtin_amdgcn_mfma_f32_16x16x32_bf16(af2[t2], bp[tn2], acc2[t2][tn2], 0, 0, 0);
    __syncthreads();
  }
#pragma unroll
  for (int t2 = 0; t2 < 2; t2++)
#pragma unroll
    for (int tn2 = 0; tn2 < 2; tn2++)
#pragma unroll
      for (int r = 0; r < 4; r++)
        projF[(w * 32 + t2 * 16 + quad * 4 + r) * 32 + tn2 * 16 + lrow] = acc2[t2][tn2][r];
  {
    uint4 vr0 = *(const uint4*)((const char*)RwT + (long)(n0 + (p0 >> 6)) * 64 + (p0 & 63));
    uint4 vr1 = *(const uint4*)((const char*)RwT + (long)(n0 + (p1 >> 6)) * 64 + (p1 & 63));
    *(uint4*)((char*)Bt + p0) = vr0;
    *(uint4*)((char*)Bt + p1) = vr1;
  }
  __syncthreads();
  if (tid < 128) {
    float pr[32];
#pragma unroll
    for (int j = 0; j < 32; j++) pr[j] = projF[tid * 32 + j];
    float wo[32];
#pragma unroll
    for (int k = 0; k < 8; k++) { wo[k] = gl[k] * pr[8 + k]; wo[8 + k] = -gl[k] * pr[k]; }
#pragma unroll
    for (int kp = 0; kp < 8; kp++) {
      float sv = pr[16 + kp], tv = pr[24 + kp];
#pragma unroll
      for (int k = 0; k < 8; k++) {
        float gpb = gl[k] * pr[8 + k], gpa = gl[k] * pr[k];
        sv += gpb * Ml[k * 8 + kp]       - gpa * Ml[64 + k * 8 + kp];
        tv += gpb * Ml[128 + k * 8 + kp] - gpa * Ml[192 + k * 8 + kp];
      }
      wo[16 + kp] = gl[8 + kp] * sv;
      wo[24 + kp] = gl[16 + kp] * tv;
    }
#pragma unroll
    for (int j = 0; j < 32; j++) wLds[tid * 32 + j] = f2bf(wo[j]);
  }
  __syncthreads();
  {
    bf16x8 af[4], bq[4];
#pragma unroll
    for (int tm = 0; tm < 4; tm++)
      af[tm] = *(const bf16x8*)(wLds + (mw + tm * 16 + lrow) * 32 + quad * 8);
#pragma unroll
    for (int tn = 0; tn < 4; tn++)
      bq[tn] = *(const bf16x8*)(Bt + (nw + tn * 16 + lrow) * 32 + quad * 8);
#pragma unroll
    for (int tm = 0; tm < 4; tm++)
#pragma unroll
      for (int tn = 0; tn < 4; tn++)
        acc[tm][tn] = __builtin_amdgcn_mfma_f32_16x16x32_bf16(af[tm], bq[tn], acc[tm][tn], 0, 0, 0);
  }
#pragma unroll
  for (int tn = 0; tn < 4; tn++) {
    const int col = n0 + nw + tn * 16 + lrow;
    const float bias = bb[col];
#pragma unroll
    for (int tm = 0; tm < 4; tm++)
#pragma unroll
      for (int r = 0; r < 4; r++) {
        long row = m0 + mw + tm * 16 + quad * 4 + r;
        out[row * DD + col] = acc[tm][tn][r] + bias;
      }
  }
}

// ---------------------------------------------------------------------------
extern "C" void kernel_launch(void* const* d_in, const int* in_sizes, int n_in,
                              void* d_out, int out_size, void* d_ws, size_t ws_size,
                              hipStream_t stream) {
  const float* x   = (const float*)d_in[0];
  const float* Wb  = (const float*)d_in[1];
  const float* bb  = (const float*)d_in[2];
  const float* lng = (const float*)d_in[3];
  const float* lnb = (const float*)d_in[4];
  const float* Wc1 = (const float*)d_in[5];
  const float* bc1 = (const float*)d_in[6];
  const float* Wc2 = (const float*)d_in[7];
  const float* bc2 = (const float*)d_in[8];
  const float* Wrg = (const float*)d_in[9];
  const float* brg = (const float*)d_in[10];
  const float* Wrc = (const float*)d_in[11];
  const float* brc = (const float*)d_in[12];
  const float* Wsg = (const float*)d_in[13];
  const float* bsg = (const float*)d_in[14];
  const float* Wlc = (const float*)d_in[15];
  const float* blc = (const float*)d_in[16];
  const float* Us  = (const float*)d_in[17];
  const float* Vs  = (const float*)d_in[18];
  const float* Ul  = (const float*)d_in[19];
  const float* Vl  = (const float*)d_in[20];
  const float* Ao  = (const float*)d_in[21];
  const float* Bo  = (const float*)d_in[22];

  char* ws = (char*)d_ws;
  float* pooled = (float*)(ws + 0);         //  4*1024 f32  [memset]
  float* AWBW   = (float*)(ws + 16384);     // 16*1024 f32  [memset]
  float* h1pre  = (float*)(ws + 81920);     //  4*128 f32   [memset] -> 83968
  float* gates  = (float*)(ws + 83968);     //  4*32  f32   -> 84480
  float* Mbuf   = (float*)(ws + 84480);     //  256   f32   -> 85504
  u32*   cntH   = (u32*)  (ws + 85504);     //  counters [memset]
  u32*   cntS   = (u32*)  (ws + 85508);
  u32*   cntW   = (u32*)  (ws + 85512);     //  -> 85568
  u16*   RwT    = (u16*)  (ws + 85568);     // 1024*32 bf16 -> 151104
  u16*   Pb     = (u16*)  (ws + 151104);    // 32*1024 bf16 -> 216640
  u16*   Wt     = (u16*)  (ws + 216640);    // 1024*1024 bf16 (2 MB) -> 2313792
  u16*   xb     = (u16*)  (ws + 2313792);   // 16384*1024 bf16 (32 MB), mode A
  float* out    = (float*)d_out;

  const bool modeA = ws_size >= (size_t)2313792 + 33554432;

  (void)hipMemsetAsync(d_ws, 0, 85568, stream);   // pooled+AWBW+h1pre+cnts
  if (modeA) {
    k01m<true><<<880, 256, 0, stream>>>(x, xb, pooled, Wb, Ao, Bo, Us, Ul,
                                        AWBW, Mbuf, Pb, Wt,
                                        lng, lnb, Wc1, h1pre, Vs, Vl,
                                        bc1, Wc2, bc2, Wrg, brg, Wrc, brc,
                                        Wsg, bsg, Wlc, blc, gates, RwT,
                                        cntS, cntH, cntW);
    k3b_fused<<<512, 256, 0, stream>>>(xb, Wt, Pb, gates, Mbuf, RwT, bb, out);
  } else {
    k01m<false><<<880, 256, 0, stream>>>(x, xb, pooled, Wb, Ao, Bo, Us, Ul,
                                         AWBW, Mbuf, Pb, Wt,
                                         lng, lnb, Wc1, h1pre, Vs, Vl,
                                         bc1, Wc2, bc2, Wrg, brg, Wrc, brc,
                                         Wsg, bsg, Wlc, blc, gates, RwT,
                                         cntS, cntH, cntW);
    k3_fused<false><<<1024, 256, 0, stream>>>(x, xb, Wt, Pb, gates, Mbuf, RwT, bb, out);
  }
}